// Round 2
// baseline (215.780 us; speedup 1.0000x reference)
//
#include <hip/hip_runtime.h>
#include <hip/hip_bf16.h>
#include <stdint.h>

#define NROWS 2048
#define DIM   4096
#define NACT  684
#define INV_TEMP 10.0f
#define NTILE 136        // 16*17/2 upper-triangle 128x128 tiles
#define KSPLIT 4
#define KSEG  1024       // DIM / KSPLIT
#define KIT   16         // KSEG / 64 (MX K-step = 64)
#define FP8_SCALE 16.0f  // Y stored as fp8(y*16); dot = 256*cos
#define PART_SCALE (1.0f / 256.0f)

// s_waitcnt immediates (gfx9/CDNA: vmcnt[3:0]@0, expcnt@4, lgkmcnt@8, vmcnt[5:4]@14)
#define WAITCNT_VM0   0x0F70
#define WAITCNT_VM4   0x0F74
#define WAITCNT_VM8   0x0F78
#define WAITCNT_VM12  0x0F7C

typedef __attribute__((ext_vector_type(4))) float floatx4;
typedef __attribute__((ext_vector_type(16))) float floatx16;
typedef __attribute__((ext_vector_type(4))) int intx4;
typedef __attribute__((ext_vector_type(8))) int intx8;
typedef __attribute__((ext_vector_type(8))) short shortx8;
typedef __attribute__((ext_vector_type(8))) unsigned short ushortx8;

static __device__ __forceinline__ unsigned short f32_to_bf16(float f) {
  union { float f; unsigned int u; } v; v.f = f;
  unsigned int u = v.u;
  unsigned int r = u + 0x7fffu + ((u >> 16) & 1u);
  return (unsigned short)(r >> 16);
}
static __device__ __forceinline__ float bf16_to_f32(unsigned short u) {
  union { unsigned int u; float f; } v; v.u = ((unsigned int)u) << 16;
  return v.f;
}
static __device__ __forceinline__ unsigned short f32_to_f16(float f) {
  _Float16 h = (_Float16)f;
  union { _Float16 h; unsigned short u; } v; v.h = h;
  return v.u;
}
static __device__ __forceinline__ float f16_to_f32(unsigned short u) {
  union { unsigned short u; _Float16 h; } v; v.u = u;
  return (float)v.h;
}

// ------- Kernel 1A: per-row L2 norm + fp8 e4m3 convert (y*16); zeroes T/out/cnt -------
// Loads coalesced: lane i reads float4 #(i + t*256) (stride-1 within instruction).
__global__ __launch_bounds__(256) void k_normconv_fp8(const float* __restrict__ X,
                                                      unsigned char* __restrict__ Yq,
                                                      float* __restrict__ T,
                                                      float* __restrict__ out,
                                                      int* __restrict__ cnt) {
  const int row = blockIdx.x;
  if (threadIdx.x == 0) T[row] = 0.f;             // replaces hipMemsetAsync(T)
  if (row == 0 && threadIdx.x == 64) *out = 0.f;  // replaces hipMemsetAsync(out)
  if (row < NTILE && threadIdx.x == 128) cnt[row] = 0;
  const float4* xr = (const float4*)(X + (size_t)row * DIM);
  float4 v[4];
  float s = 0.f;
#pragma unroll
  for (int t = 0; t < 4; t++) {
    float4 w = xr[threadIdx.x + t * 256];
    v[t] = w;
    s += w.x * w.x + w.y * w.y + w.z * w.z + w.w * w.w;
  }
#pragma unroll
  for (int off = 32; off > 0; off >>= 1) s += __shfl_down(s, off, 64);
  __shared__ float wsum[4];
  if ((threadIdx.x & 63) == 0) wsum[threadIdx.x >> 6] = s;
  __syncthreads();
  const float total = wsum[0] + wsum[1] + wsum[2] + wsum[3];
  const float sc = FP8_SCALE / fmaxf(sqrtf(total), 1e-30f);
  unsigned int* yr = (unsigned int*)(Yq + (size_t)row * DIM);
#pragma unroll
  for (int t = 0; t < 4; t++) {
    float4 w = v[t];
    unsigned int r0 = __builtin_amdgcn_cvt_pk_fp8_f32(w.x * sc, w.y * sc, 0, false);
    r0 = __builtin_amdgcn_cvt_pk_fp8_f32(w.z * sc, w.w * sc, r0, true);
    yr[threadIdx.x + t * 256] = r0;
  }
}

// ------- Kernel 2A: symmetric split-K(4) MX-fp8 GEMM, fused per-tile combine -------
// XCD swizzle: 544 blocks = 8 XCDs x 68; a tile's 4 kz siblings stay on one XCD
// (L2-local P partials, simultaneous finish). Last-arriving sibling (threadfence +
// acq_rel atomic counter, no spin) performs the combine for the whole tile: sums the
// 4 bf16 partials, writes fp16 S (both triangles via LDS transpose) and exp-rowsums T.
__global__ __launch_bounds__(256) void k_gemm_fused(const unsigned char* __restrict__ Yq,
                                                    unsigned short* __restrict__ P,
                                                    unsigned short* __restrict__ S,
                                                    float* __restrict__ T,
                                                    int* __restrict__ cnt) {
  __shared__ __attribute__((aligned(16))) unsigned char lds[4 * 16384];
  __shared__ int last_flag;
  // bijective XCD-aware swizzle (544 = 8*68): consecutive logical jobs share an XCD.
  const int bid0 = blockIdx.x;
  const int bid = (bid0 & 7) * 68 + (bid0 >> 3);
  const int kz = bid & 3;
  const int t  = bid >> 2;
  int ti = 0, rem = t;
  while (rem >= 16 - ti) { rem -= 16 - ti; ti++; }
  const int tj = ti + rem;
  const int row0 = ti * 128;
  const int col0 = tj * 128;
  const int kbase = kz * KSEG;

  const int tid  = threadIdx.x;
  const int lane = tid & 63;
  const int wave = tid >> 6;
  const int wr = wave >> 1;
  const int wc = wave & 1;

  floatx16 zero = {0.f, 0.f, 0.f, 0.f, 0.f, 0.f, 0.f, 0.f,
                   0.f, 0.f, 0.f, 0.f, 0.f, 0.f, 0.f, 0.f};
  floatx16 acc[2][2];
#pragma unroll
  for (int i = 0; i < 2; i++)
#pragma unroll
    for (int j = 0; j < 2; j++) acc[i][j] = zero;

  // staging: thread t covers LDS bytes [16t,16t+16): row r2=t>>2, chunk t&3.
  // Source column pre-swizzled (linear dest + inverse-swizzled source + swizzled read).
  const int r2  = tid >> 2;
  const int c16 = tid & 3;
  const unsigned int swst = (unsigned)(((r2 >> 1) & 3) << 4);
  const unsigned int colst = ((unsigned)(c16 << 4)) ^ swst;
  const unsigned char* gA = Yq + (size_t)(row0 + r2) * DIM + kbase + colst;
  const unsigned char* gB = Yq + (size_t)(col0 + r2) * DIM + kbase + colst;

#define ISSUE(st, koff)                                                                  \
  do {                                                                                   \
    __builtin_amdgcn_global_load_lds(                                                    \
        (const __attribute__((address_space(1))) void*)(gA + (koff)),                    \
        (__attribute__((address_space(3))) void*)(lds + (st) * 16384 + tid * 16),        \
        16, 0, 0);                                                                       \
    __builtin_amdgcn_global_load_lds(                                                    \
        (const __attribute__((address_space(1))) void*)(gA + (size_t)64 * DIM + (koff)), \
        (__attribute__((address_space(3))) void*)(lds + (st) * 16384 + 4096 + tid * 16), \
        16, 0, 0);                                                                       \
    __builtin_amdgcn_global_load_lds(                                                    \
        (const __attribute__((address_space(1))) void*)(gB + (koff)),                    \
        (__attribute__((address_space(3))) void*)(lds + (st) * 16384 + 8192 + tid * 16), \
        16, 0, 0);                                                                       \
    __builtin_amdgcn_global_load_lds(                                                    \
        (const __attribute__((address_space(1))) void*)(gB + (size_t)64 * DIM + (koff)), \
        (__attribute__((address_space(3))) void*)(lds + (st) * 16384 + 12288 + tid * 16),\
        16, 0, 0);                                                                       \
  } while (0)

#define COMPUTE(st)                                                                      \
  do {                                                                                   \
    const unsigned char* bA = lds + (st) * 16384;                                        \
    const unsigned char* bB = bA + 8192;                                                 \
    const unsigned int c0 = (unsigned)((lane >> 5) << 5);                                \
    intx8 af[2], bf[2];                                                                  \
    _Pragma("unroll")                                                                    \
    for (int mi = 0; mi < 2; mi++) {                                                     \
      const int r = wr * 64 + mi * 32 + (lane & 31);                                     \
      const unsigned int sw = (unsigned)(((r >> 1) & 3) << 4);                           \
      const unsigned char* base = bA + r * 64;                                           \
      intx4 lo = *(const intx4*)(base + (c0 ^ sw));                                      \
      intx4 hi = *(const intx4*)(base + ((c0 ^ sw) ^ 16u));                              \
      intx8 v;                                                                           \
      v[0] = lo[0]; v[1] = lo[1]; v[2] = lo[2]; v[3] = lo[3];                            \
      v[4] = hi[0]; v[5] = hi[1]; v[6] = hi[2]; v[7] = hi[3];                            \
      af[mi] = v;                                                                        \
    }                                                                                    \
    _Pragma("unroll")                                                                    \
    for (int ni = 0; ni < 2; ni++) {                                                     \
      const int r = wc * 64 + ni * 32 + (lane & 31);                                     \
      const unsigned int sw = (unsigned)(((r >> 1) & 3) << 4);                           \
      const unsigned char* base = bB + r * 64;                                           \
      intx4 lo = *(const intx4*)(base + (c0 ^ sw));                                      \
      intx4 hi = *(const intx4*)(base + ((c0 ^ sw) ^ 16u));                              \
      intx8 v;                                                                           \
      v[0] = lo[0]; v[1] = lo[1]; v[2] = lo[2]; v[3] = lo[3];                            \
      v[4] = hi[0]; v[5] = hi[1]; v[6] = hi[2]; v[7] = hi[3];                            \
      bf[ni] = v;                                                                        \
    }                                                                                    \
    _Pragma("unroll")                                                                    \
    for (int mi = 0; mi < 2; mi++)                                                       \
      _Pragma("unroll")                                                                  \
      for (int ni = 0; ni < 2; ni++)                                                     \
        acc[mi][ni] = __builtin_amdgcn_mfma_scale_f32_32x32x64_f8f6f4(                   \
            af[mi], bf[ni], acc[mi][ni], 0, 0, 0, 0x7F7F7F7F, 0, 0x7F7F7F7F);            \
  } while (0)

  ISSUE(0, 0);
  ISSUE(1, 64);
  ISSUE(2, 128);
#pragma unroll 4
  for (int k = 0; k < KIT; k++) {
    const int cur = k & 3;
    if (k < KIT - 3) {
      ISSUE((k + 3) & 3, (k + 3) * 64);
      __builtin_amdgcn_s_waitcnt(WAITCNT_VM12);
    } else if (k == KIT - 3) {
      __builtin_amdgcn_s_waitcnt(WAITCNT_VM8);
    } else if (k == KIT - 2) {
      __builtin_amdgcn_s_waitcnt(WAITCNT_VM4);
    } else {
      __builtin_amdgcn_s_waitcnt(WAITCNT_VM0);
    }
    __builtin_amdgcn_sched_barrier(0);
    __builtin_amdgcn_s_barrier();
    COMPUTE(cur);
    if (k < KIT - 1) {
      __builtin_amdgcn_s_barrier();
      __builtin_amdgcn_sched_barrier(0);
    }
  }

#undef ISSUE
#undef COMPUTE

  // Epilogue: partial = acc/256 (bf16), COL-MAJOR per tile (col*128 + row).
  // 32x32 C/D layout: col = lane&31, row = (reg&3) + 8*(reg>>2) + 4*(lane>>5).
  {
    unsigned short* dst = P + (size_t)(t * KSPLIT + kz) * 16384;
    const int cc = lane & 31;
    const int cr = (lane >> 5) * 4;
#pragma unroll
    for (int mi = 0; mi < 2; mi++) {
#pragma unroll
      for (int ni = 0; ni < 2; ni++) {
        const int col = wc * 64 + ni * 32 + cc;
#pragma unroll
        for (int q = 0; q < 4; q++) {
          const int row = wr * 64 + mi * 32 + q * 8 + cr;
          unsigned int d0 = (unsigned int)f32_to_bf16(acc[mi][ni][q * 4 + 0] * PART_SCALE) |
                            ((unsigned int)f32_to_bf16(acc[mi][ni][q * 4 + 1] * PART_SCALE) << 16);
          unsigned int d1 = (unsigned int)f32_to_bf16(acc[mi][ni][q * 4 + 2] * PART_SCALE) |
                            ((unsigned int)f32_to_bf16(acc[mi][ni][q * 4 + 3] * PART_SCALE) << 16);
          uint2 v; v.x = d0; v.y = d1;
          *(uint2*)(dst + (size_t)col * 128 + row) = v;
        }
      }
    }
  }

  // ---- last-arriver handoff (standard threadfence-reduction idiom, no spin) ----
  __threadfence();
  __syncthreads();
  if (tid == 0) {
    int old = __hip_atomic_fetch_add(&cnt[t], 1, __ATOMIC_ACQ_REL, __HIP_MEMORY_SCOPE_AGENT);
    last_flag = (old == KSPLIT - 1) ? 1 : 0;
  }
  __syncthreads();
  if (!last_flag) return;

  // ---- combine for tile t (all 4 col-quarters), LDS reused for transpose staging ----
  float* tileS = (float*)lds;            // [32][132]
  float* tileE = (float*)(lds + 16896);  // [32][132]
  const int gr = ti * 128, gc = tj * 128;
  const int cl = tid >> 3;               // local col 0..31
  const int q  = tid & 7;                // row chunk

  for (int h = 0; h < 4; h++) {
    if (h) __syncthreads();              // protect tile overwrite from prev reads
    const int c0 = h * 32;
    float acc2[16];
#pragma unroll
    for (int j = 0; j < 16; j++) acc2[j] = 0.f;
#pragma unroll
    for (int kz2 = 0; kz2 < KSPLIT; kz2++) {
      const ushortx8* p = (const ushortx8*)(P + (size_t)(t * KSPLIT + kz2) * 16384 +
                                            (size_t)(c0 + cl) * 128 + q * 16);
#pragma unroll
      for (int c = 0; c < 2; c++) {
        ushortx8 u = p[c];
#pragma unroll
        for (int e = 0; e < 8; e++) acc2[c * 8 + e] += bf16_to_f32((unsigned short)u[e]);
      }
    }
    float cs = 0.f;
    unsigned short hv[16];
#pragma unroll
    for (int j = 0; j < 16; j++) {
      float v = acc2[j] * INV_TEMP;
      float ev = __expf(v);
      hv[j] = f32_to_f16(v);
      tileS[cl * 132 + q * 16 + j] = v;
      tileE[cl * 132 + q * 16 + j] = ev;
      cs += ev;
    }
    // mirror write: S[gc+col][gr + q*16 .. +16]
    {
      uint4* srow = (uint4*)(S + (size_t)(gc + c0 + cl) * NROWS + gr + q * 16);
#pragma unroll
      for (int u = 0; u < 2; u++) {
        uint4 w;
        w.x = (unsigned int)hv[u * 8 + 0] | ((unsigned int)hv[u * 8 + 1] << 16);
        w.y = (unsigned int)hv[u * 8 + 2] | ((unsigned int)hv[u * 8 + 3] << 16);
        w.z = (unsigned int)hv[u * 8 + 4] | ((unsigned int)hv[u * 8 + 5] << 16);
        w.w = (unsigned int)hv[u * 8 + 6] | ((unsigned int)hv[u * 8 + 7] << 16);
        srow[u] = w;
      }
    }
    cs += __shfl_xor(cs, 1, 64);
    cs += __shfl_xor(cs, 2, 64);
    cs += __shfl_xor(cs, 4, 64);
    if (q == 0) atomicAdd(&T[gc + c0 + cl], cs);

    if (ti != tj) {
      __syncthreads();
      const int r = tid >> 1;
      const int hh = tid & 1;
      float rs = 0.f;
      unsigned short hv2[16];
#pragma unroll
      for (int e = 0; e < 16; e++) {
        hv2[e] = f32_to_f16(tileS[(hh * 16 + e) * 132 + r]);
        rs += tileE[(hh * 16 + e) * 132 + r];
      }
      uint4* drow = (uint4*)(S + (size_t)(gr + r) * NROWS + gc + c0 + hh * 16);
#pragma unroll
      for (int u = 0; u < 2; u++) {
        uint4 w;
        w.x = (unsigned int)hv2[u * 8 + 0] | ((unsigned int)hv2[u * 8 + 1] << 16);
        w.y = (unsigned int)hv2[u * 8 + 2] | ((unsigned int)hv2[u * 8 + 3] << 16);
        w.z = (unsigned int)hv2[u * 8 + 4] | ((unsigned int)hv2[u * 8 + 5] << 16);
        w.w = (unsigned int)hv2[u * 8 + 6] | ((unsigned int)hv2[u * 8 + 7] << 16);
        drow[u] = w;
      }
      rs += __shfl_xor(rs, 1, 64);
      if (hh == 0) atomicAdd(&T[gr + r], rs);
    }
  }
}

// ---- Kernel 4A: fused Dsum + pair losses. Block per p; 6 waves do the 6 Dsum gathers,
// then 7 lanes of wave 0 do the pair terms from LDS. One global atomic per block. ----
__global__ __launch_bounds__(384) void k_tail(const unsigned short* __restrict__ S,
                                              const float* __restrict__ T,
                                              float* __restrict__ out) {
  __shared__ float ds_s[6];
  const int p = blockIdx.x;
  const int a = 12 * (p >> 2) + (p & 3);
  const int tid = threadIdx.x;
  const int k = tid >> 6;            // 0..5
  const int lane = tid & 63;
  const int row = (a + 4 * k) & (NROWS - 1);
  const int m = a >> 2;
  const int c = a & 3;
  const uint2* sr = (const uint2*)(S + (size_t)row * NROWS);
  float s = 0.f;
  {
    uint2 v0 = sr[(m + lane) & 511];
    uint2 v1 = sr[(m + 64 + lane) & 511];
    unsigned short e0 = (c < 2) ? (unsigned short)(v0.x >> (16 * c))
                                : (unsigned short)(v0.y >> (16 * (c - 2)));
    unsigned short e1 = (c < 2) ? (unsigned short)(v1.x >> (16 * c))
                                : (unsigned short)(v1.y >> (16 * (c - 2)));
    s += __expf(f16_to_f32(e0)) + __expf(f16_to_f32(e1));
    if (lane < 32) {
      uint2 v2 = sr[(m + 128 + lane) & 511];
      unsigned short e2 = (c < 2) ? (unsigned short)(v2.x >> (16 * c))
                                  : (unsigned short)(v2.y >> (16 * (c - 2)));
      s += __expf(f16_to_f32(e2));
    }
  }
#pragma unroll
  for (int off = 32; off > 0; off >>= 1) s += __shfl_down(s, off, 64);
  if (lane == 0) ds_s[k] = T[row] - s;
  __syncthreads();

  float r = 0.f;
  if (tid < 7) {
    const int pa[7] = {0, 1, 0, 3, 4, 1, 2};
    const int pb[7] = {1, 2, 3, 4, 5, 4, 5};
    const int ra = (a + 4 * pa[tid]) & (NROWS - 1);
    const int rb = (a + 4 * pb[tid]) & (NROWS - 1);
    const float num = f16_to_f32(S[(size_t)ra * NROWS + rb]);
    const float en = __expf(num);
    r = __logf(en + ds_s[pa[tid]]) + __logf(en + ds_s[pb[tid]]) - 2.f * num;
  }
  if (tid < 64) {
    r += __shfl_down(r, 4, 64);
    r += __shfl_down(r, 2, 64);
    r += __shfl_down(r, 1, 64);
    if (tid == 0) atomicAdd(out, r * (1.0f / (6.0f * 512.0f)));
  }
}

// ------------- Path B kernels (fallback when ws is small; fp32 S) -------------
__global__ __launch_bounds__(256) void k_normconv(const float* __restrict__ X,
                                                  unsigned short* __restrict__ Y) {
  const int row = blockIdx.x;
  const float4* xr = (const float4*)(X + (size_t)row * DIM);
  float4 v[4];
  float s = 0.f;
#pragma unroll
  for (int t = 0; t < 4; t++) {
    float4 w = xr[threadIdx.x + t * 256];
    v[t] = w;
    s += w.x * w.x + w.y * w.y + w.z * w.z + w.w * w.w;
  }
#pragma unroll
  for (int off = 32; off > 0; off >>= 1) s += __shfl_down(s, off, 64);
  __shared__ float wsum[4];
  if ((threadIdx.x & 63) == 0) wsum[threadIdx.x >> 6] = s;
  __syncthreads();
  const float total = wsum[0] + wsum[1] + wsum[2] + wsum[3];
  const float inv = 1.0f / fmaxf(sqrtf(total), 1e-30f);
  ushort4* yr = (ushort4*)(Y + (size_t)row * DIM);
#pragma unroll
  for (int t = 0; t < 4; t++) {
    float4 w = v[t];
    ushort4 o;
    o.x = f32_to_bf16(w.x * inv);
    o.y = f32_to_bf16(w.y * inv);
    o.z = f32_to_bf16(w.z * inv);
    o.w = f32_to_bf16(w.w * inv);
    yr[threadIdx.x + t * 256] = o;
  }
}

__global__ __launch_bounds__(256) void k_gemm(const unsigned short* __restrict__ Y,
                                              float* __restrict__ S) {
  __shared__ __attribute__((aligned(16))) unsigned short sA[128 * 32];
  __shared__ __attribute__((aligned(16))) unsigned short sB[128 * 32];
  const int tid  = threadIdx.x;
  const int lane = tid & 63;
  const int wave = tid >> 6;
  const int wr = wave >> 1;
  const int wc = wave & 1;
  const int row0 = blockIdx.y * 128;
  const int col0 = blockIdx.x * 128;

  floatx4 zero = {0.f, 0.f, 0.f, 0.f};
  floatx4 acc[4][4];
#pragma unroll
  for (int i = 0; i < 4; i++)
#pragma unroll
    for (int j = 0; j < 4; j++) acc[i][j] = zero;

  const int sr = tid >> 2;
  const int sc = (tid & 3) * 8;
  const unsigned short* gA0 = Y + (size_t)(row0 + sr) * DIM + sc;
  const unsigned short* gA1 = gA0 + (size_t)64 * DIM;
  const unsigned short* gB0 = Y + (size_t)(col0 + sr) * DIM + sc;
  const unsigned short* gB1 = gB0 + (size_t)64 * DIM;

  const int fr = lane & 15;
  const int fc = (lane >> 4) * 8;

  for (int k0 = 0; k0 < DIM; k0 += 32) {
    __builtin_amdgcn_global_load_lds(
        (const __attribute__((address_space(1))) void*)(gA0 + k0),
        (__attribute__((address_space(3))) void*)(sA + tid * 8), 16, 0, 0);
    __builtin_amdgcn_global_load_lds(
        (const __attribute__((address_space(1))) void*)(gA1 + k0),
        (__attribute__((address_space(3))) void*)(sA + 2048 + tid * 8), 16, 0, 0);
    __builtin_amdgcn_global_load_lds(
        (const __attribute__((address_space(1))) void*)(gB0 + k0),
        (__attribute__((address_space(3))) void*)(sB + tid * 8), 16, 0, 0);
    __builtin_amdgcn_global_load_lds(
        (const __attribute__((address_space(1))) void*)(gB1 + k0),
        (__attribute__((address_space(3))) void*)(sB + 2048 + tid * 8), 16, 0, 0);
    __syncthreads();

    shortx8 af[4], bf[4];
#pragma unroll
    for (int mi = 0; mi < 4; mi++)
      af[mi] = *(const shortx8*)(sA + (wr * 64 + mi * 16 + fr) * 32 + fc);
#pragma unroll
    for (int ni = 0; ni < 4; ni++)
      bf[ni] = *(const shortx8*)(sB + (wc * 64 + ni * 16 + fr) * 32 + fc);
#pragma unroll
    for (int mi = 0; mi < 4; mi++)
#pragma unroll
      for (int ni = 0; ni < 4; ni++)
        acc[mi][ni] = __builtin_amdgcn_mfma_f32_16x16x32_bf16(af[mi], bf[ni], acc[mi][ni], 0, 0, 0);
    __syncthreads();
  }

  const int cc  = lane & 15;
  const int cr4 = (lane >> 4) * 4;
#pragma unroll
  for (int mi = 0; mi < 4; mi++) {
    const int row = row0 + wr * 64 + mi * 16 + cr4;
#pragma unroll
    for (int ni = 0; ni < 4; ni++) {
      const int col = col0 + wc * 64 + ni * 16 + cc;
      float* dst = S + (size_t)row * NROWS + col;
#pragma unroll
      for (int r = 0; r < 4; r++) dst[(size_t)r * NROWS] = acc[mi][ni][r] * INV_TEMP;
    }
  }
}

__global__ __launch_bounds__(256) void k_rowsum(const float* __restrict__ S,
                                                float* __restrict__ T) {
  const int row = blockIdx.x;
  const float* sr = S + (size_t)row * NROWS;
  float s = 0.f;
  for (int b = threadIdx.x; b < NROWS; b += 256) s += __expf(sr[b]);
#pragma unroll
  for (int off = 32; off > 0; off >>= 1) s += __shfl_down(s, off, 64);
  __shared__ float wsum[4];
  if ((threadIdx.x & 63) == 0) wsum[threadIdx.x >> 6] = s;
  __syncthreads();
  if (threadIdx.x == 0) T[row] = wsum[0] + wsum[1] + wsum[2] + wsum[3];
}

__global__ __launch_bounds__(64) void k_dsum(const float* __restrict__ S,
                                             const float* __restrict__ T,
                                             float* __restrict__ Ds) {
  const int p = blockIdx.x;
  const int k = blockIdx.y;
  const int a = 12 * (p >> 2) + (p & 3);
  const int lane = threadIdx.x;
  const int row = (a + 4 * k) & (NROWS - 1);
  const int m = a >> 2;
  const int c = a & 3;
  const float4* sr4 = (const float4*)(S + (size_t)row * NROWS);
  float s = 0.f;
  {
    float4 v0 = sr4[(m + lane) & 511];
    float4 v1 = sr4[(m + 64 + lane) & 511];
    float e0 = c == 0 ? v0.x : c == 1 ? v0.y : c == 2 ? v0.z : v0.w;
    float e1 = c == 0 ? v1.x : c == 1 ? v1.y : c == 2 ? v1.z : v1.w;
    s += __expf(e0) + __expf(e1);
    if (lane < 32) {
      float4 v2 = sr4[(m + 128 + lane) & 511];
      float e2 = c == 0 ? v2.x : c == 1 ? v2.y : c == 2 ? v2.z : v2.w;
      s += __expf(e2);
    }
  }
#pragma unroll
  for (int off = 32; off > 0; off >>= 1) s += __shfl_down(s, off, 64);
  if (lane == 0) Ds[p * 6 + k] = T[row] - s;
}

__global__ __launch_bounds__(256) void k_final(const float* __restrict__ S,
                                               const float* __restrict__ Ds,
                                               float* __restrict__ out) {
  const int pa[7] = {0, 1, 0, 3, 4, 1, 2};
  const int pb[7] = {1, 2, 3, 4, 5, 4, 5};
  const int idx = blockIdx.x * 256 + threadIdx.x;
  float s = 0.f;
  if (idx < NACT * 7) {
    const int p = idx / 7;
    const int q = idx - p * 7;
    const int a0 = 12 * (p >> 2) + (p & 3);
    const int ra = (a0 + 4 * pa[q]) & (NROWS - 1);
    const int rb = (a0 + 4 * pb[q]) & (NROWS - 1);
    const float num = S[(size_t)ra * NROWS + rb];
    const float en = __expf(num);
    s = __logf(en + Ds[p * 6 + pa[q]]) + __logf(en + Ds[p * 6 + pb[q]]) - 2.f * num;
  }
#pragma unroll
  for (int off = 32; off > 0; off >>= 1) s += __shfl_down(s, off, 64);
  if ((threadIdx.x & 63) == 0) atomicAdd(out, s * (1.0f / (6.0f * 512.0f)));
}

extern "C" void kernel_launch(void* const* d_in, const int* in_sizes, int n_in,
                              void* d_out, int out_size, void* d_ws, size_t ws_size,
                              hipStream_t stream) {
  const float* X = (const float*)d_in[0];
  char* ws = (char*)d_ws;
  float* out = (float*)d_out;

  const size_t pOff = (size_t)32 * 1024 * 1024;
  const size_t pBytes = (size_t)NTILE * KSPLIT * 16384 * 2;     // 17.8 MB bf16 partials
  const size_t needA = pOff + pBytes + 8192 + NACT * 6 * 4 + 256;

  if (ws_size >= needA) {
    unsigned char* Yq = (unsigned char*)ws;                       // 8 MB fp8
    unsigned short* S16 = (unsigned short*)(ws + (size_t)16 * 1024 * 1024); // 8 MB fp16
    unsigned short* P = (unsigned short*)(ws + pOff);
    float* T  = (float*)(ws + pOff + pBytes);
    int* cnt  = (int*)(ws + pOff + pBytes + 8192);
    hipLaunchKernelGGL(k_normconv_fp8, dim3(NROWS), dim3(256), 0, stream, X, Yq, T, out, cnt);
    hipLaunchKernelGGL(k_gemm_fused, dim3(NTILE * KSPLIT), dim3(256), 0, stream, Yq, P, S16, T, cnt);
    hipLaunchKernelGGL(k_tail, dim3(NACT), dim3(384), 0, stream, S16, T, out);
  } else {
    unsigned short* Y = (unsigned short*)ws;                      // 16 MB bf16
    float* S = (float*)(ws + (size_t)16 * 1024 * 1024);           // 16 MB fp32
    float* T  = (float*)(ws + pOff);
    float* Ds = (float*)(ws + pOff + 8192);
    hipMemsetAsync(out, 0, sizeof(float), stream);
    hipLaunchKernelGGL(k_normconv, dim3(NROWS), dim3(256), 0, stream, X, Y);
    hipLaunchKernelGGL(k_gemm, dim3(16, 16), dim3(256), 0, stream, Y, S);
    hipLaunchKernelGGL(k_rowsum, dim3(NROWS), dim3(256), 0, stream, S, T);
    hipLaunchKernelGGL(k_dsum, dim3(NACT, 6), dim3(64), 0, stream, S, T, Ds);
    hipLaunchKernelGGL(k_final, dim3((NACT * 7 + 255) / 256), dim3(256), 0, stream, S, Ds, out);
  }
}

// Round 3
// 112.444 us; speedup vs baseline: 1.9190x; 1.9190x over previous
//
#include <hip/hip_runtime.h>
#include <hip/hip_bf16.h>
#include <stdint.h>

#define NROWS 2048
#define DIM   4096
#define NACT  684
#define INV_TEMP 10.0f
#define NTILE 136        // 16*17/2 upper-triangle 128x128 tiles
#define KSPLIT 4
#define KSEG  1024       // DIM / KSPLIT
#define KIT   16         // KSEG / 64 (MX K-step = 64)
#define FP8_SCALE 16.0f  // Y stored as fp8(y*16); dot = 256*cos
#define PART_SCALE (1.0f / 256.0f)

// s_waitcnt immediates (gfx9/CDNA: vmcnt[3:0]@0, expcnt@4, lgkmcnt@8, vmcnt[5:4]@14)
#define WAITCNT_VM0   0x0F70
#define WAITCNT_VM4   0x0F74
#define WAITCNT_VM8   0x0F78

typedef __attribute__((ext_vector_type(4))) float floatx4;
typedef __attribute__((ext_vector_type(16))) float floatx16;
typedef __attribute__((ext_vector_type(4))) int intx4;
typedef __attribute__((ext_vector_type(8))) int intx8;
typedef __attribute__((ext_vector_type(8))) short shortx8;
typedef __attribute__((ext_vector_type(8))) unsigned short ushortx8;

static __device__ __forceinline__ unsigned short f32_to_bf16(float f) {
  union { float f; unsigned int u; } v; v.f = f;
  unsigned int u = v.u;
  unsigned int r = u + 0x7fffu + ((u >> 16) & 1u);
  return (unsigned short)(r >> 16);
}
static __device__ __forceinline__ float bf16_to_f32(unsigned short u) {
  union { unsigned int u; float f; } v; v.u = ((unsigned int)u) << 16;
  return v.f;
}
static __device__ __forceinline__ unsigned short f32_to_f16(float f) {
  _Float16 h = (_Float16)f;
  union { _Float16 h; unsigned short u; } v; v.h = h;
  return v.u;
}
static __device__ __forceinline__ float f16_to_f32(unsigned short u) {
  union { unsigned short u; _Float16 h; } v; v.u = u;
  return (float)v.h;
}

// ------- Kernel 1A: per-row L2 norm + fp8 e4m3 convert (y*16); zeroes T/out -------
// Loads coalesced: lane i reads float4 #(i + t*256) (stride-1 within instruction).
__global__ __launch_bounds__(256) void k_normconv_fp8(const float* __restrict__ X,
                                                      unsigned char* __restrict__ Yq,
                                                      float* __restrict__ T,
                                                      float* __restrict__ out) {
  const int row = blockIdx.x;
  if (threadIdx.x == 0) T[row] = 0.f;             // replaces hipMemsetAsync(T)
  if (row == 0 && threadIdx.x == 64) *out = 0.f;  // replaces hipMemsetAsync(out)
  const float4* xr = (const float4*)(X + (size_t)row * DIM);
  float4 v[4];
  float s = 0.f;
#pragma unroll
  for (int t = 0; t < 4; t++) {
    float4 w = xr[threadIdx.x + t * 256];
    v[t] = w;
    s += w.x * w.x + w.y * w.y + w.z * w.z + w.w * w.w;
  }
#pragma unroll
  for (int off = 32; off > 0; off >>= 1) s += __shfl_down(s, off, 64);
  __shared__ float wsum[4];
  if ((threadIdx.x & 63) == 0) wsum[threadIdx.x >> 6] = s;
  __syncthreads();
  const float total = wsum[0] + wsum[1] + wsum[2] + wsum[3];
  const float sc = FP8_SCALE / fmaxf(sqrtf(total), 1e-30f);
  unsigned int* yr = (unsigned int*)(Yq + (size_t)row * DIM);
#pragma unroll
  for (int t = 0; t < 4; t++) {
    float4 w = v[t];
    unsigned int r0 = __builtin_amdgcn_cvt_pk_fp8_f32(w.x * sc, w.y * sc, 0, false);
    r0 = __builtin_amdgcn_cvt_pk_fp8_f32(w.z * sc, w.w * sc, r0, true);
    yr[threadIdx.x + t * 256] = r0;
  }
}

// ------- Kernel 2A: symmetric split-K(4) MX-fp8 GEMM, 3-stage ring -------
// 3 stages x 16 KB = 48 KB LDS -> 3 blocks/CU -> 544 blocks fit in ONE occupancy round
// (vs 2 rounds at 64 KB) and 12 waves/CU for latency hiding. Prefetch depth 2,
// counted vmcnt(8/4/0). XCD swizzle (544 = 8*68, bijective): each XCD owns a
// contiguous stripe of ~17 tiles -> A-panels L2-resident per XCD. NO cross-block
// fences/atomics (round-2 post-mortem: per-block device-scope fence = L2 wb/inv storm).
__global__ __launch_bounds__(256) void k_gemm_mx(const unsigned char* __restrict__ Yq,
                                                 unsigned short* __restrict__ P) {
  __shared__ __attribute__((aligned(16))) unsigned char lds[3 * 16384];
  const int bid0 = blockIdx.x;
  const int bid = (bid0 & 7) * 68 + (bid0 >> 3);
  const int kz = bid & 3;
  const int t  = bid >> 2;
  int ti = 0, rem = t;
  while (rem >= 16 - ti) { rem -= 16 - ti; ti++; }
  const int tj = ti + rem;
  const int row0 = ti * 128;
  const int col0 = tj * 128;
  const int kbase = kz * KSEG;

  const int tid  = threadIdx.x;
  const int lane = tid & 63;
  const int wave = tid >> 6;
  const int wr = wave >> 1;
  const int wc = wave & 1;

  floatx16 zero = {0.f, 0.f, 0.f, 0.f, 0.f, 0.f, 0.f, 0.f,
                   0.f, 0.f, 0.f, 0.f, 0.f, 0.f, 0.f, 0.f};
  floatx16 acc[2][2];
#pragma unroll
  for (int i = 0; i < 2; i++)
#pragma unroll
    for (int j = 0; j < 2; j++) acc[i][j] = zero;

  // staging: thread t covers LDS bytes [16t,16t+16): row r2=t>>2, chunk t&3.
  // Source column pre-swizzled (linear dest + inverse-swizzled source + swizzled read).
  const int r2  = tid >> 2;
  const int c16 = tid & 3;
  const unsigned int swst = (unsigned)(((r2 >> 1) & 3) << 4);
  const unsigned int colst = ((unsigned)(c16 << 4)) ^ swst;
  const unsigned char* gA = Yq + (size_t)(row0 + r2) * DIM + kbase + colst;
  const unsigned char* gB = Yq + (size_t)(col0 + r2) * DIM + kbase + colst;

#define ISSUE(st, koff)                                                                  \
  do {                                                                                   \
    __builtin_amdgcn_global_load_lds(                                                    \
        (const __attribute__((address_space(1))) void*)(gA + (koff)),                    \
        (__attribute__((address_space(3))) void*)(lds + (st) * 16384 + tid * 16),        \
        16, 0, 0);                                                                       \
    __builtin_amdgcn_global_load_lds(                                                    \
        (const __attribute__((address_space(1))) void*)(gA + (size_t)64 * DIM + (koff)), \
        (__attribute__((address_space(3))) void*)(lds + (st) * 16384 + 4096 + tid * 16), \
        16, 0, 0);                                                                       \
    __builtin_amdgcn_global_load_lds(                                                    \
        (const __attribute__((address_space(1))) void*)(gB + (koff)),                    \
        (__attribute__((address_space(3))) void*)(lds + (st) * 16384 + 8192 + tid * 16), \
        16, 0, 0);                                                                       \
    __builtin_amdgcn_global_load_lds(                                                    \
        (const __attribute__((address_space(1))) void*)(gB + (size_t)64 * DIM + (koff)), \
        (__attribute__((address_space(3))) void*)(lds + (st) * 16384 + 12288 + tid * 16),\
        16, 0, 0);                                                                       \
  } while (0)

#define COMPUTE(st)                                                                      \
  do {                                                                                   \
    const unsigned char* bA = lds + (st) * 16384;                                        \
    const unsigned char* bB = bA + 8192;                                                 \
    const unsigned int c0 = (unsigned)((lane >> 5) << 5);                                \
    intx8 af[2], bf[2];                                                                  \
    _Pragma("unroll")                                                                    \
    for (int mi = 0; mi < 2; mi++) {                                                     \
      const int r = wr * 64 + mi * 32 + (lane & 31);                                     \
      const unsigned int sw = (unsigned)(((r >> 1) & 3) << 4);                           \
      const unsigned char* base = bA + r * 64;                                           \
      intx4 lo = *(const intx4*)(base + (c0 ^ sw));                                      \
      intx4 hi = *(const intx4*)(base + ((c0 ^ sw) ^ 16u));                              \
      intx8 v;                                                                           \
      v[0] = lo[0]; v[1] = lo[1]; v[2] = lo[2]; v[3] = lo[3];                            \
      v[4] = hi[0]; v[5] = hi[1]; v[6] = hi[2]; v[7] = hi[3];                            \
      af[mi] = v;                                                                        \
    }                                                                                    \
    _Pragma("unroll")                                                                    \
    for (int ni = 0; ni < 2; ni++) {                                                     \
      const int r = wc * 64 + ni * 32 + (lane & 31);                                     \
      const unsigned int sw = (unsigned)(((r >> 1) & 3) << 4);                           \
      const unsigned char* base = bB + r * 64;                                           \
      intx4 lo = *(const intx4*)(base + (c0 ^ sw));                                      \
      intx4 hi = *(const intx4*)(base + ((c0 ^ sw) ^ 16u));                              \
      intx8 v;                                                                           \
      v[0] = lo[0]; v[1] = lo[1]; v[2] = lo[2]; v[3] = lo[3];                            \
      v[4] = hi[0]; v[5] = hi[1]; v[6] = hi[2]; v[7] = hi[3];                            \
      bf[ni] = v;                                                                        \
    }                                                                                    \
    _Pragma("unroll")                                                                    \
    for (int mi = 0; mi < 2; mi++)                                                       \
      _Pragma("unroll")                                                                  \
      for (int ni = 0; ni < 2; ni++)                                                     \
        acc[mi][ni] = __builtin_amdgcn_mfma_scale_f32_32x32x64_f8f6f4(                   \
            af[mi], bf[ni], acc[mi][ni], 0, 0, 0, 0x7F7F7F7F, 0, 0x7F7F7F7F);            \
  } while (0)

  // 3-stage ring: stage (k+2)%3 is re-issued at iter k; its previous contents were
  // consumed at iter k-1 and the trailing barrier of iter k-1 protects the overwrite
  // (same discipline as the verified 4-stage version, depth reduced 3->2).
  ISSUE(0, 0);
  ISSUE(1, 64);
#pragma unroll
  for (int k = 0; k < KIT; k++) {
    const int cur = k % 3;
    if (k < KIT - 2) {
      ISSUE((k + 2) % 3, (k + 2) * 64);
      __builtin_amdgcn_s_waitcnt(WAITCNT_VM8);
    } else if (k == KIT - 2) {
      __builtin_amdgcn_s_waitcnt(WAITCNT_VM4);
    } else {
      __builtin_amdgcn_s_waitcnt(WAITCNT_VM0);
    }
    __builtin_amdgcn_sched_barrier(0);
    __builtin_amdgcn_s_barrier();
    COMPUTE(cur);
    if (k < KIT - 1) {
      __builtin_amdgcn_s_barrier();
      __builtin_amdgcn_sched_barrier(0);
    }
  }

#undef ISSUE
#undef COMPUTE

  // Epilogue: partial = acc/256 (bf16), COL-MAJOR per tile (col*128 + row).
  // 32x32 C/D layout: col = lane&31, row = (reg&3) + 8*(reg>>2) + 4*(lane>>5).
  unsigned short* dst = P + (size_t)(t * KSPLIT + kz) * 16384;
  const int cc = lane & 31;
  const int cr = (lane >> 5) * 4;
#pragma unroll
  for (int mi = 0; mi < 2; mi++) {
#pragma unroll
    for (int ni = 0; ni < 2; ni++) {
      const int col = wc * 64 + ni * 32 + cc;
#pragma unroll
      for (int q = 0; q < 4; q++) {
        const int row = wr * 64 + mi * 32 + q * 8 + cr;
        unsigned int d0 = (unsigned int)f32_to_bf16(acc[mi][ni][q * 4 + 0] * PART_SCALE) |
                          ((unsigned int)f32_to_bf16(acc[mi][ni][q * 4 + 1] * PART_SCALE) << 16);
        unsigned int d1 = (unsigned int)f32_to_bf16(acc[mi][ni][q * 4 + 2] * PART_SCALE) |
                          ((unsigned int)f32_to_bf16(acc[mi][ni][q * 4 + 3] * PART_SCALE) << 16);
        uint2 v; v.x = d0; v.y = d1;
        *(uint2*)(dst + (size_t)col * 128 + row) = v;
      }
    }
  }
}

// ---- Kernel 3A: combine partials (col-major) -> S (fp16, both triangles) + exp-rowsum T ----
__global__ __launch_bounds__(256) void k_combine(const unsigned short* __restrict__ P,
                                                 unsigned short* __restrict__ S,
                                                 float* __restrict__ T) {
  __shared__ float tileS[32][132];
  __shared__ float tileE[32][132];
  const int t = blockIdx.x;
  const int h = blockIdx.y;          // col quarter
  int ti = 0, rem = t;
  while (rem >= 16 - ti) { rem -= 16 - ti; ti++; }
  const int tj = ti + rem;
  const int gr = ti * 128, gc = tj * 128;
  const int c0 = h * 32;
  const int tid = threadIdx.x;
  const int cl = tid >> 3;           // local col 0..31
  const int q  = tid & 7;            // row chunk

  float acc[16];
#pragma unroll
  for (int j = 0; j < 16; j++) acc[j] = 0.f;
#pragma unroll
  for (int kz = 0; kz < KSPLIT; kz++) {
    const ushortx8* p = (const ushortx8*)(P + (size_t)(t * KSPLIT + kz) * 16384 +
                                          (size_t)(c0 + cl) * 128 + q * 16);
#pragma unroll
    for (int c = 0; c < 2; c++) {
      ushortx8 u = p[c];
#pragma unroll
      for (int e = 0; e < 8; e++) acc[c * 8 + e] += bf16_to_f32((unsigned short)u[e]);
    }
  }
  float cs = 0.f;
  unsigned short hv[16];
#pragma unroll
  for (int j = 0; j < 16; j++) {
    float v = acc[j] * INV_TEMP;
    float ev = __expf(v);
    hv[j] = f32_to_f16(v);
    tileS[cl][q * 16 + j] = v;
    tileE[cl][q * 16 + j] = ev;
    cs += ev;
  }
  // mirror write: S[gc+col][gr + q*16 .. +16]  (16 halfs = 2x uint4)
  {
    uint4* srow = (uint4*)(S + (size_t)(gc + c0 + cl) * NROWS + gr + q * 16);
#pragma unroll
    for (int u = 0; u < 2; u++) {
      uint4 w;
      w.x = (unsigned int)hv[u * 8 + 0] | ((unsigned int)hv[u * 8 + 1] << 16);
      w.y = (unsigned int)hv[u * 8 + 2] | ((unsigned int)hv[u * 8 + 3] << 16);
      w.z = (unsigned int)hv[u * 8 + 4] | ((unsigned int)hv[u * 8 + 5] << 16);
      w.w = (unsigned int)hv[u * 8 + 6] | ((unsigned int)hv[u * 8 + 7] << 16);
      srow[u] = w;
    }
  }
  cs += __shfl_xor(cs, 1, 64);
  cs += __shfl_xor(cs, 2, 64);
  cs += __shfl_xor(cs, 4, 64);
  if (q == 0) atomicAdd(&T[gc + c0 + cl], cs);

  if (ti != tj) {
    __syncthreads();
    const int r = tid >> 1;
    const int hh = tid & 1;
    float rs = 0.f;
    unsigned short hv2[16];
#pragma unroll
    for (int e = 0; e < 16; e++) {
      hv2[e] = f32_to_f16(tileS[hh * 16 + e][r]);
      rs += tileE[hh * 16 + e][r];
    }
    uint4* drow = (uint4*)(S + (size_t)(gr + r) * NROWS + gc + c0 + hh * 16);
#pragma unroll
    for (int u = 0; u < 2; u++) {
      uint4 w;
      w.x = (unsigned int)hv2[u * 8 + 0] | ((unsigned int)hv2[u * 8 + 1] << 16);
      w.y = (unsigned int)hv2[u * 8 + 2] | ((unsigned int)hv2[u * 8 + 3] << 16);
      w.z = (unsigned int)hv2[u * 8 + 4] | ((unsigned int)hv2[u * 8 + 5] << 16);
      w.w = (unsigned int)hv2[u * 8 + 6] | ((unsigned int)hv2[u * 8 + 7] << 16);
      drow[u] = w;
    }
    rs += __shfl_xor(rs, 1, 64);
    if (hh == 0) atomicAdd(&T[gr + r], rs);
  }
}

// ---- Kernel 4A: fused Dsum + pair losses. Block per p; 6 waves do the 6 Dsum gathers,
// then 7 lanes of wave 0 do the pair terms from LDS. One global atomic per block. ----
__global__ __launch_bounds__(384) void k_tail(const unsigned short* __restrict__ S,
                                              const float* __restrict__ T,
                                              float* __restrict__ out) {
  __shared__ float ds_s[6];
  const int p = blockIdx.x;
  const int a = 12 * (p >> 2) + (p & 3);
  const int tid = threadIdx.x;
  const int k = tid >> 6;            // 0..5
  const int lane = tid & 63;
  const int row = (a + 4 * k) & (NROWS - 1);
  const int m = a >> 2;
  const int c = a & 3;
  const uint2* sr = (const uint2*)(S + (size_t)row * NROWS);
  float s = 0.f;
  {
    uint2 v0 = sr[(m + lane) & 511];
    uint2 v1 = sr[(m + 64 + lane) & 511];
    unsigned short e0 = (c < 2) ? (unsigned short)(v0.x >> (16 * c))
                                : (unsigned short)(v0.y >> (16 * (c - 2)));
    unsigned short e1 = (c < 2) ? (unsigned short)(v1.x >> (16 * c))
                                : (unsigned short)(v1.y >> (16 * (c - 2)));
    s += __expf(f16_to_f32(e0)) + __expf(f16_to_f32(e1));
    if (lane < 32) {
      uint2 v2 = sr[(m + 128 + lane) & 511];
      unsigned short e2 = (c < 2) ? (unsigned short)(v2.x >> (16 * c))
                                  : (unsigned short)(v2.y >> (16 * (c - 2)));
      s += __expf(f16_to_f32(e2));
    }
  }
#pragma unroll
  for (int off = 32; off > 0; off >>= 1) s += __shfl_down(s, off, 64);
  if (lane == 0) ds_s[k] = T[row] - s;
  __syncthreads();

  float r = 0.f;
  if (tid < 7) {
    const int pa[7] = {0, 1, 0, 3, 4, 1, 2};
    const int pb[7] = {1, 2, 3, 4, 5, 4, 5};
    const int ra = (a + 4 * pa[tid]) & (NROWS - 1);
    const int rb = (a + 4 * pb[tid]) & (NROWS - 1);
    const float num = f16_to_f32(S[(size_t)ra * NROWS + rb]);
    const float en = __expf(num);
    r = __logf(en + ds_s[pa[tid]]) + __logf(en + ds_s[pb[tid]]) - 2.f * num;
  }
  if (tid < 64) {
    r += __shfl_down(r, 4, 64);
    r += __shfl_down(r, 2, 64);
    r += __shfl_down(r, 1, 64);
    if (tid == 0) atomicAdd(out, r * (1.0f / (6.0f * 512.0f)));
  }
}

// ------------- Path B kernels (fallback when ws is small; fp32 S) -------------
__global__ __launch_bounds__(256) void k_normconv(const float* __restrict__ X,
                                                  unsigned short* __restrict__ Y) {
  const int row = blockIdx.x;
  const float4* xr = (const float4*)(X + (size_t)row * DIM);
  float4 v[4];
  float s = 0.f;
#pragma unroll
  for (int t = 0; t < 4; t++) {
    float4 w = xr[threadIdx.x + t * 256];
    v[t] = w;
    s += w.x * w.x + w.y * w.y + w.z * w.z + w.w * w.w;
  }
#pragma unroll
  for (int off = 32; off > 0; off >>= 1) s += __shfl_down(s, off, 64);
  __shared__ float wsum[4];
  if ((threadIdx.x & 63) == 0) wsum[threadIdx.x >> 6] = s;
  __syncthreads();
  const float total = wsum[0] + wsum[1] + wsum[2] + wsum[3];
  const float inv = 1.0f / fmaxf(sqrtf(total), 1e-30f);
  ushort4* yr = (ushort4*)(Y + (size_t)row * DIM);
#pragma unroll
  for (int t = 0; t < 4; t++) {
    float4 w = v[t];
    ushort4 o;
    o.x = f32_to_bf16(w.x * inv);
    o.y = f32_to_bf16(w.y * inv);
    o.z = f32_to_bf16(w.z * inv);
    o.w = f32_to_bf16(w.w * inv);
    yr[threadIdx.x + t * 256] = o;
  }
}

__global__ __launch_bounds__(256) void k_gemm(const unsigned short* __restrict__ Y,
                                              float* __restrict__ S) {
  __shared__ __attribute__((aligned(16))) unsigned short sA[128 * 32];
  __shared__ __attribute__((aligned(16))) unsigned short sB[128 * 32];
  const int tid  = threadIdx.x;
  const int lane = tid & 63;
  const int wave = tid >> 6;
  const int wr = wave >> 1;
  const int wc = wave & 1;
  const int row0 = blockIdx.y * 128;
  const int col0 = blockIdx.x * 128;

  floatx4 zero = {0.f, 0.f, 0.f, 0.f};
  floatx4 acc[4][4];
#pragma unroll
  for (int i = 0; i < 4; i++)
#pragma unroll
    for (int j = 0; j < 4; j++) acc[i][j] = zero;

  const int sr = tid >> 2;
  const int sc = (tid & 3) * 8;
  const unsigned short* gA0 = Y + (size_t)(row0 + sr) * DIM + sc;
  const unsigned short* gA1 = gA0 + (size_t)64 * DIM;
  const unsigned short* gB0 = Y + (size_t)(col0 + sr) * DIM + sc;
  const unsigned short* gB1 = gB0 + (size_t)64 * DIM;

  const int fr = lane & 15;
  const int fc = (lane >> 4) * 8;

  for (int k0 = 0; k0 < DIM; k0 += 32) {
    __builtin_amdgcn_global_load_lds(
        (const __attribute__((address_space(1))) void*)(gA0 + k0),
        (__attribute__((address_space(3))) void*)(sA + tid * 8), 16, 0, 0);
    __builtin_amdgcn_global_load_lds(
        (const __attribute__((address_space(1))) void*)(gA1 + k0),
        (__attribute__((address_space(3))) void*)(sA + 2048 + tid * 8), 16, 0, 0);
    __builtin_amdgcn_global_load_lds(
        (const __attribute__((address_space(1))) void*)(gB0 + k0),
        (__attribute__((address_space(3))) void*)(sB + tid * 8), 16, 0, 0);
    __builtin_amdgcn_global_load_lds(
        (const __attribute__((address_space(1))) void*)(gB1 + k0),
        (__attribute__((address_space(3))) void*)(sB + 2048 + tid * 8), 16, 0, 0);
    __syncthreads();

    shortx8 af[4], bf[4];
#pragma unroll
    for (int mi = 0; mi < 4; mi++)
      af[mi] = *(const shortx8*)(sA + (wr * 64 + mi * 16 + fr) * 32 + fc);
#pragma unroll
    for (int ni = 0; ni < 4; ni++)
      bf[ni] = *(const shortx8*)(sB + (wc * 64 + ni * 16 + fr) * 32 + fc);
#pragma unroll
    for (int mi = 0; mi < 4; mi++)
#pragma unroll
      for (int ni = 0; ni < 4; ni++)
        acc[mi][ni] = __builtin_amdgcn_mfma_f32_16x16x32_bf16(af[mi], bf[ni], acc[mi][ni], 0, 0, 0);
    __syncthreads();
  }

  const int cc  = lane & 15;
  const int cr4 = (lane >> 4) * 4;
#pragma unroll
  for (int mi = 0; mi < 4; mi++) {
    const int row = row0 + wr * 64 + mi * 16 + cr4;
#pragma unroll
    for (int ni = 0; ni < 4; ni++) {
      const int col = col0 + wc * 64 + ni * 16 + cc;
      float* dst = S + (size_t)row * NROWS + col;
#pragma unroll
      for (int r = 0; r < 4; r++) dst[(size_t)r * NROWS] = acc[mi][ni][r] * INV_TEMP;
    }
  }
}

__global__ __launch_bounds__(256) void k_rowsum(const float* __restrict__ S,
                                                float* __restrict__ T) {
  const int row = blockIdx.x;
  const float* sr = S + (size_t)row * NROWS;
  float s = 0.f;
  for (int b = threadIdx.x; b < NROWS; b += 256) s += __expf(sr[b]);
#pragma unroll
  for (int off = 32; off > 0; off >>= 1) s += __shfl_down(s, off, 64);
  __shared__ float wsum[4];
  if ((threadIdx.x & 63) == 0) wsum[threadIdx.x >> 6] = s;
  __syncthreads();
  if (threadIdx.x == 0) T[row] = wsum[0] + wsum[1] + wsum[2] + wsum[3];
}

__global__ __launch_bounds__(64) void k_dsum(const float* __restrict__ S,
                                             const float* __restrict__ T,
                                             float* __restrict__ Ds) {
  const int p = blockIdx.x;
  const int k = blockIdx.y;
  const int a = 12 * (p >> 2) + (p & 3);
  const int lane = threadIdx.x;
  const int row = (a + 4 * k) & (NROWS - 1);
  const int m = a >> 2;
  const int c = a & 3;
  const float4* sr4 = (const float4*)(S + (size_t)row * NROWS);
  float s = 0.f;
  {
    float4 v0 = sr4[(m + lane) & 511];
    float4 v1 = sr4[(m + 64 + lane) & 511];
    float e0 = c == 0 ? v0.x : c == 1 ? v0.y : c == 2 ? v0.z : v0.w;
    float e1 = c == 0 ? v1.x : c == 1 ? v1.y : c == 2 ? v1.z : v1.w;
    s += __expf(e0) + __expf(e1);
    if (lane < 32) {
      float4 v2 = sr4[(m + 128 + lane) & 511];
      float e2 = c == 0 ? v2.x : c == 1 ? v2.y : c == 2 ? v2.z : v2.w;
      s += __expf(e2);
    }
  }
#pragma unroll
  for (int off = 32; off > 0; off >>= 1) s += __shfl_down(s, off, 64);
  if (lane == 0) Ds[p * 6 + k] = T[row] - s;
}

__global__ __launch_bounds__(256) void k_final(const float* __restrict__ S,
                                               const float* __restrict__ Ds,
                                               float* __restrict__ out) {
  const int pa[7] = {0, 1, 0, 3, 4, 1, 2};
  const int pb[7] = {1, 2, 3, 4, 5, 4, 5};
  const int idx = blockIdx.x * 256 + threadIdx.x;
  float s = 0.f;
  if (idx < NACT * 7) {
    const int p = idx / 7;
    const int q = idx - p * 7;
    const int a0 = 12 * (p >> 2) + (p & 3);
    const int ra = (a0 + 4 * pa[q]) & (NROWS - 1);
    const int rb = (a0 + 4 * pb[q]) & (NROWS - 1);
    const float num = S[(size_t)ra * NROWS + rb];
    const float en = __expf(num);
    s = __logf(en + Ds[p * 6 + pa[q]]) + __logf(en + Ds[p * 6 + pb[q]]) - 2.f * num;
  }
#pragma unroll
  for (int off = 32; off > 0; off >>= 1) s += __shfl_down(s, off, 64);
  if ((threadIdx.x & 63) == 0) atomicAdd(out, s * (1.0f / (6.0f * 512.0f)));
}

extern "C" void kernel_launch(void* const* d_in, const int* in_sizes, int n_in,
                              void* d_out, int out_size, void* d_ws, size_t ws_size,
                              hipStream_t stream) {
  const float* X = (const float*)d_in[0];
  char* ws = (char*)d_ws;
  float* out = (float*)d_out;

  const size_t pOff = (size_t)32 * 1024 * 1024;
  const size_t pBytes = (size_t)NTILE * KSPLIT * 16384 * 2;     // 17.8 MB bf16 partials
  const size_t needA = pOff + pBytes + 8192 + NACT * 6 * 4 + 256;

  if (ws_size >= needA) {
    unsigned char* Yq = (unsigned char*)ws;                       // 8 MB fp8
    unsigned short* S16 = (unsigned short*)(ws + (size_t)16 * 1024 * 1024); // 8 MB fp16
    unsigned short* P = (unsigned short*)(ws + pOff);
    float* T  = (float*)(ws + pOff + pBytes);
    hipLaunchKernelGGL(k_normconv_fp8, dim3(NROWS), dim3(256), 0, stream, X, Yq, T, out);
    hipLaunchKernelGGL(k_gemm_mx, dim3(NTILE * KSPLIT), dim3(256), 0, stream, Yq, P);
    hipLaunchKernelGGL(k_combine, dim3(NTILE, 4), dim3(256), 0, stream, P, S16, T);
    hipLaunchKernelGGL(k_tail, dim3(NACT), dim3(384), 0, stream, S16, T, out);
  } else {
    unsigned short* Y = (unsigned short*)ws;                      // 16 MB bf16
    float* S = (float*)(ws + (size_t)16 * 1024 * 1024);           // 16 MB fp32
    float* T  = (float*)(ws + pOff);
    float* Ds = (float*)(ws + pOff + 8192);
    hipMemsetAsync(out, 0, sizeof(float), stream);
    hipLaunchKernelGGL(k_normconv, dim3(NROWS), dim3(256), 0, stream, X, Y);
    hipLaunchKernelGGL(k_gemm, dim3(16, 16), dim3(256), 0, stream, Y, S);
    hipLaunchKernelGGL(k_rowsum, dim3(NROWS), dim3(256), 0, stream, S, T);
    hipLaunchKernelGGL(k_dsum, dim3(NACT, 6), dim3(64), 0, stream, S, T, Ds);
    hipLaunchKernelGGL(k_final, dim3((NACT * 7 + 255) / 256), dim3(256), 0, stream, S, Ds, out);
  }
}

// Round 4
// 108.731 us; speedup vs baseline: 1.9845x; 1.0342x over previous
//
#include <hip/hip_runtime.h>
#include <hip/hip_bf16.h>
#include <stdint.h>

#define NROWS 2048
#define DIM   4096
#define NACT  684
#define INV_TEMP 10.0f
#define NPANEL 32        // 2048/64 row panels
#define NTILE64 528      // 32*33/2 upper-triangle 64x64 tiles
#define NK 64            // DIM / 64 K-steps
#define FP8_SCALE 16.0f  // Y stored as fp8(y*16); dot = 256*cos
#define OUT_SCALE (INV_TEMP / 256.0f)

// s_waitcnt immediates (gfx9/CDNA: vmcnt[3:0]@0, expcnt@4, lgkmcnt@8, vmcnt[5:4]@14)
#define WAITCNT_VM0   0x0F70
#define WAITCNT_VM2   0x0F72
#define WAITCNT_VM4   0x0F74
#define WAITCNT_VM6   0x0F76

typedef __attribute__((ext_vector_type(4))) float floatx4;
typedef __attribute__((ext_vector_type(16))) float floatx16;
typedef __attribute__((ext_vector_type(4))) int intx4;
typedef __attribute__((ext_vector_type(8))) int intx8;
typedef __attribute__((ext_vector_type(8))) short shortx8;
typedef __attribute__((ext_vector_type(8))) unsigned short ushortx8;

static __device__ __forceinline__ unsigned short f32_to_bf16(float f) {
  union { float f; unsigned int u; } v; v.f = f;
  unsigned int u = v.u;
  unsigned int r = u + 0x7fffu + ((u >> 16) & 1u);
  return (unsigned short)(r >> 16);
}
static __device__ __forceinline__ float bf16_to_f32(unsigned short u) {
  union { unsigned int u; float f; } v; v.u = ((unsigned int)u) << 16;
  return v.f;
}
static __device__ __forceinline__ unsigned short f32_to_f16(float f) {
  _Float16 h = (_Float16)f;
  union { _Float16 h; unsigned short u; } v; v.h = h;
  return v.u;
}
static __device__ __forceinline__ float f16_to_f32(unsigned short u) {
  union { unsigned short u; _Float16 h; } v; v.u = u;
  return (float)v.h;
}

// ------- Kernel 1A: per-row L2 norm + fp8 e4m3 convert (y*16); zeroes T/out -------
__global__ __launch_bounds__(256) void k_normconv_fp8(const float* __restrict__ X,
                                                      unsigned char* __restrict__ Yq,
                                                      float* __restrict__ T,
                                                      float* __restrict__ out) {
  const int row = blockIdx.x;
  if (threadIdx.x == 0) T[row] = 0.f;             // replaces hipMemsetAsync(T)
  if (row == 0 && threadIdx.x == 64) *out = 0.f;  // replaces hipMemsetAsync(out)
  const float4* xr = (const float4*)(X + (size_t)row * DIM);
  float4 v[4];
  float s = 0.f;
#pragma unroll
  for (int t = 0; t < 4; t++) {
    float4 w = xr[threadIdx.x + t * 256];
    v[t] = w;
    s += w.x * w.x + w.y * w.y + w.z * w.z + w.w * w.w;
  }
#pragma unroll
  for (int off = 32; off > 0; off >>= 1) s += __shfl_down(s, off, 64);
  __shared__ float wsum[4];
  if ((threadIdx.x & 63) == 0) wsum[threadIdx.x >> 6] = s;
  __syncthreads();
  const float total = wsum[0] + wsum[1] + wsum[2] + wsum[3];
  const float sc = FP8_SCALE / fmaxf(sqrtf(total), 1e-30f);
  unsigned int* yr = (unsigned int*)(Yq + (size_t)row * DIM);
#pragma unroll
  for (int t = 0; t < 4; t++) {
    float4 w = v[t];
    unsigned int r0 = __builtin_amdgcn_cvt_pk_fp8_f32(w.x * sc, w.y * sc, 0, false);
    r0 = __builtin_amdgcn_cvt_pk_fp8_f32(w.z * sc, w.w * sc, r0, true);
    yr[threadIdx.x + t * 256] = r0;
  }
}

// ------- Kernel 2A: full-K 64x64-tile MX-fp8 GEMM with fused S/T epilogue -------
// 528 tiles (upper triangle of 32 panels), each block does K=4096 and owns its whole
// output tile -> no split-K partials, no combine kernel, no cross-block handoff.
// 4-stage ring (8 KB/stage), counted vmcnt(6/4/2/0), LDS source-side swizzle.
// Epilogue: exp/f16 in LDS, col-sums (= mirrored row-sums via symmetry) + row-sums
// atomically into T, coalesced S16 write of tile + mirror. f32 accumulation throughout.
__global__ __launch_bounds__(256) void k_gemm_full(const unsigned char* __restrict__ Yq,
                                                   unsigned short* __restrict__ S,
                                                   float* __restrict__ T) {
  __shared__ __attribute__((aligned(16))) unsigned char lds[32768];
  // bijective XCD-aware swizzle (528 = 8*66): consecutive logical tiles share an XCD.
  const int bid0 = blockIdx.x;
  const int t = (bid0 & 7) * 66 + (bid0 >> 3);
  int ti = 0, rem = t;
  while (rem >= NPANEL - ti) { rem -= NPANEL - ti; ti++; }
  const int tj = ti + rem;
  const int gr = ti * 64;
  const int gc = tj * 64;

  const int tid  = threadIdx.x;
  const int lane = tid & 63;
  const int wave = tid >> 6;
  const int wr = wave >> 1;
  const int wc = wave & 1;

  floatx16 acc = {0.f, 0.f, 0.f, 0.f, 0.f, 0.f, 0.f, 0.f,
                  0.f, 0.f, 0.f, 0.f, 0.f, 0.f, 0.f, 0.f};

  // staging: thread t covers 16 B: row r2 = t>>2 (0..63), chunk c16 = t&3.
  // Source column pre-swizzled (linear LDS dest + inverse-swizzled source + swizzled read).
  const int r2  = tid >> 2;
  const int c16 = tid & 3;
  const unsigned int swst = (unsigned)(((r2 >> 1) & 3) << 4);
  const unsigned int colst = ((unsigned)(c16 << 4)) ^ swst;
  const unsigned char* gA = Yq + (size_t)(gr + r2) * DIM + colst;
  const unsigned char* gB = Yq + (size_t)(gc + r2) * DIM + colst;

#define ISSUE(st, koff)                                                                  \
  do {                                                                                   \
    __builtin_amdgcn_global_load_lds(                                                    \
        (const __attribute__((address_space(1))) void*)(gA + (koff)),                    \
        (__attribute__((address_space(3))) void*)(lds + (st) * 8192 + tid * 16),         \
        16, 0, 0);                                                                       \
    __builtin_amdgcn_global_load_lds(                                                    \
        (const __attribute__((address_space(1))) void*)(gB + (koff)),                    \
        (__attribute__((address_space(3))) void*)(lds + (st) * 8192 + 4096 + tid * 16),  \
        16, 0, 0);                                                                       \
  } while (0)

  // Fragment read: wave (wr,wc) computes quadrant rows wr*32.., cols (B-rows) wc*32..
#define COMPUTE(st)                                                                      \
  do {                                                                                   \
    const unsigned char* bA = lds + (st) * 8192;                                         \
    const unsigned char* bB = bA + 4096;                                                 \
    const unsigned int c0 = (unsigned)((lane >> 5) << 5);                                \
    const int rA = wr * 32 + (lane & 31);                                                \
    const int rB = wc * 32 + (lane & 31);                                                \
    const unsigned int swA = (unsigned)(((rA >> 1) & 3) << 4);                           \
    const unsigned int swB = (unsigned)(((rB >> 1) & 3) << 4);                           \
    const unsigned char* baseA = bA + rA * 64;                                           \
    const unsigned char* baseB = bB + rB * 64;                                           \
    intx4 alo = *(const intx4*)(baseA + (c0 ^ swA));                                     \
    intx4 ahi = *(const intx4*)(baseA + ((c0 ^ swA) ^ 16u));                             \
    intx4 blo = *(const intx4*)(baseB + (c0 ^ swB));                                     \
    intx4 bhi = *(const intx4*)(baseB + ((c0 ^ swB) ^ 16u));                             \
    intx8 af, bf;                                                                        \
    af[0] = alo[0]; af[1] = alo[1]; af[2] = alo[2]; af[3] = alo[3];                      \
    af[4] = ahi[0]; af[5] = ahi[1]; af[6] = ahi[2]; af[7] = ahi[3];                      \
    bf[0] = blo[0]; bf[1] = blo[1]; bf[2] = blo[2]; bf[3] = blo[3];                      \
    bf[4] = bhi[0]; bf[5] = bhi[1]; bf[6] = bhi[2]; bf[7] = bhi[3];                      \
    acc = __builtin_amdgcn_mfma_scale_f32_32x32x64_f8f6f4(                               \
        af, bf, acc, 0, 0, 0, 0x7F7F7F7F, 0, 0x7F7F7F7F);                                \
  } while (0)

  ISSUE(0, 0);
  ISSUE(1, 64);
  ISSUE(2, 128);
#pragma unroll 4
  for (int k = 0; k < NK; k++) {
    const int cur = k & 3;
    if (k < NK - 3) {
      ISSUE((k + 3) & 3, (k + 3) * 64);
      __builtin_amdgcn_s_waitcnt(WAITCNT_VM6);
    } else if (k == NK - 3) {
      __builtin_amdgcn_s_waitcnt(WAITCNT_VM4);
    } else if (k == NK - 2) {
      __builtin_amdgcn_s_waitcnt(WAITCNT_VM2);
    } else {
      __builtin_amdgcn_s_waitcnt(WAITCNT_VM0);
    }
    __builtin_amdgcn_sched_barrier(0);
    __builtin_amdgcn_s_barrier();
    COMPUTE(cur);
    if (k < NK - 1) {
      __builtin_amdgcn_s_barrier();
      __builtin_amdgcn_sched_barrier(0);
    }
  }

#undef ISSUE
#undef COMPUTE

  // ---- fused epilogue (LDS reused; all staging reads are done) ----
  // 32x32 C/D layout: col = lane&31, row = (reg&3) + 8*(reg>>2) + 4*(lane>>5).
  unsigned short* tile16 = (unsigned short*)lds;        // [64][66] f16   (8448 B)
  float* tileE   = (float*)(lds + 8448);                // [64][65] float (16640 B)
  float* colpart = (float*)(lds + 25088);               // [2][64]        (512 B)
  __syncthreads();

  {
    const int col = wc * 32 + (lane & 31);
    float evsum = 0.f;
#pragma unroll
    for (int i = 0; i < 16; i++) {
      const int row = wr * 32 + (i & 3) + 8 * (i >> 2) + 4 * (lane >> 5);
      const float v = acc[i] * OUT_SCALE;
      const float ev = __expf(v);
      tile16[row * 66 + col] = f32_to_f16(v);
      tileE[row * 65 + col] = ev;
      evsum += ev;
    }
    evsum += __shfl_xor(evsum, 32, 64);
    if (lane < 32) colpart[wr * 64 + col] = evsum;   // wave-unique slot, no atomic
  }
  __syncthreads();

  // col sums -> T[gc+c]  (symmetry: column sum == mirrored row sum)
  if (tid < 64) atomicAdd(&T[gc + tid], colpart[tid] + colpart[64 + tid]);

  // main tile write: S[gr+r][gc .. gc+63], coalesced
  {
    const int r = tid >> 2, seg = tid & 3;
    const unsigned int* q = (const unsigned int*)tile16 + (r * 33 + seg * 8);
    uint4 w0, w1;
    w0.x = q[0]; w0.y = q[1]; w0.z = q[2]; w0.w = q[3];
    w1.x = q[4]; w1.y = q[5]; w1.z = q[6]; w1.w = q[7];
    uint4* dst = (uint4*)(S + (size_t)(gr + r) * NROWS + gc + seg * 16);
    dst[0] = w0; dst[1] = w1;
  }

  if (ti != tj) {
    // row sums -> T[gr+r]
    if (tid < 64) {
      float rs = 0.f;
#pragma unroll 8
      for (int c = 0; c < 64; c++) rs += tileE[tid * 65 + c];
      atomicAdd(&T[gr + tid], rs);
    }
    // mirror write: S[gc+c][gr .. gr+63]
    {
      const int c = tid >> 2, seg = tid & 3;
      unsigned short tmp[16];
#pragma unroll
      for (int k = 0; k < 16; k++) tmp[k] = tile16[(seg * 16 + k) * 66 + c];
      uint4 w0, w1;
      w0.x = (unsigned int)tmp[0]  | ((unsigned int)tmp[1]  << 16);
      w0.y = (unsigned int)tmp[2]  | ((unsigned int)tmp[3]  << 16);
      w0.z = (unsigned int)tmp[4]  | ((unsigned int)tmp[5]  << 16);
      w0.w = (unsigned int)tmp[6]  | ((unsigned int)tmp[7]  << 16);
      w1.x = (unsigned int)tmp[8]  | ((unsigned int)tmp[9]  << 16);
      w1.y = (unsigned int)tmp[10] | ((unsigned int)tmp[11] << 16);
      w1.z = (unsigned int)tmp[12] | ((unsigned int)tmp[13] << 16);
      w1.w = (unsigned int)tmp[14] | ((unsigned int)tmp[15] << 16);
      uint4* dst = (uint4*)(S + (size_t)(gc + c) * NROWS + gr + seg * 16);
      dst[0] = w0; dst[1] = w1;
    }
  }
}

// ---- Kernel 3A: fused Dsum + pair losses. Block per p; 6 waves do the 6 Dsum gathers,
// then 7 lanes of wave 0 do the pair terms from LDS. One global atomic per block. ----
__global__ __launch_bounds__(384) void k_tail(const unsigned short* __restrict__ S,
                                              const float* __restrict__ T,
                                              float* __restrict__ out) {
  __shared__ float ds_s[6];
  const int p = blockIdx.x;
  const int a = 12 * (p >> 2) + (p & 3);
  const int tid = threadIdx.x;
  const int k = tid >> 6;            // 0..5
  const int lane = tid & 63;
  const int row = (a + 4 * k) & (NROWS - 1);
  const int m = a >> 2;
  const int c = a & 3;
  const uint2* sr = (const uint2*)(S + (size_t)row * NROWS);
  float s = 0.f;
  {
    uint2 v0 = sr[(m + lane) & 511];
    uint2 v1 = sr[(m + 64 + lane) & 511];
    unsigned short e0 = (c < 2) ? (unsigned short)(v0.x >> (16 * c))
                                : (unsigned short)(v0.y >> (16 * (c - 2)));
    unsigned short e1 = (c < 2) ? (unsigned short)(v1.x >> (16 * c))
                                : (unsigned short)(v1.y >> (16 * (c - 2)));
    s += __expf(f16_to_f32(e0)) + __expf(f16_to_f32(e1));
    if (lane < 32) {
      uint2 v2 = sr[(m + 128 + lane) & 511];
      unsigned short e2 = (c < 2) ? (unsigned short)(v2.x >> (16 * c))
                                  : (unsigned short)(v2.y >> (16 * (c - 2)));
      s += __expf(f16_to_f32(e2));
    }
  }
#pragma unroll
  for (int off = 32; off > 0; off >>= 1) s += __shfl_down(s, off, 64);
  if (lane == 0) ds_s[k] = T[row] - s;
  __syncthreads();

  float r = 0.f;
  if (tid < 7) {
    const int pa[7] = {0, 1, 0, 3, 4, 1, 2};
    const int pb[7] = {1, 2, 3, 4, 5, 4, 5};
    const int ra = (a + 4 * pa[tid]) & (NROWS - 1);
    const int rb = (a + 4 * pb[tid]) & (NROWS - 1);
    const float num = f16_to_f32(S[(size_t)ra * NROWS + rb]);
    const float en = __expf(num);
    r = __logf(en + ds_s[pa[tid]]) + __logf(en + ds_s[pb[tid]]) - 2.f * num;
  }
  if (tid < 64) {
    r += __shfl_down(r, 4, 64);
    r += __shfl_down(r, 2, 64);
    r += __shfl_down(r, 1, 64);
    if (tid == 0) atomicAdd(out, r * (1.0f / (6.0f * 512.0f)));
  }
}

// ------------- Path B kernels (fallback when ws is small; fp32 S) -------------
__global__ __launch_bounds__(256) void k_normconv(const float* __restrict__ X,
                                                  unsigned short* __restrict__ Y) {
  const int row = blockIdx.x;
  const float4* xr = (const float4*)(X + (size_t)row * DIM);
  float4 v[4];
  float s = 0.f;
#pragma unroll
  for (int t = 0; t < 4; t++) {
    float4 w = xr[threadIdx.x + t * 256];
    v[t] = w;
    s += w.x * w.x + w.y * w.y + w.z * w.z + w.w * w.w;
  }
#pragma unroll
  for (int off = 32; off > 0; off >>= 1) s += __shfl_down(s, off, 64);
  __shared__ float wsum[4];
  if ((threadIdx.x & 63) == 0) wsum[threadIdx.x >> 6] = s;
  __syncthreads();
  const float total = wsum[0] + wsum[1] + wsum[2] + wsum[3];
  const float inv = 1.0f / fmaxf(sqrtf(total), 1e-30f);
  ushort4* yr = (ushort4*)(Y + (size_t)row * DIM);
#pragma unroll
  for (int t = 0; t < 4; t++) {
    float4 w = v[t];
    ushort4 o;
    o.x = f32_to_bf16(w.x * inv);
    o.y = f32_to_bf16(w.y * inv);
    o.z = f32_to_bf16(w.z * inv);
    o.w = f32_to_bf16(w.w * inv);
    yr[threadIdx.x + t * 256] = o;
  }
}

__global__ __launch_bounds__(256) void k_gemm(const unsigned short* __restrict__ Y,
                                              float* __restrict__ S) {
  __shared__ __attribute__((aligned(16))) unsigned short sA[128 * 32];
  __shared__ __attribute__((aligned(16))) unsigned short sB[128 * 32];
  const int tid  = threadIdx.x;
  const int lane = tid & 63;
  const int wave = tid >> 6;
  const int wr = wave >> 1;
  const int wc = wave & 1;
  const int row0 = blockIdx.y * 128;
  const int col0 = blockIdx.x * 128;

  floatx4 zero = {0.f, 0.f, 0.f, 0.f};
  floatx4 acc[4][4];
#pragma unroll
  for (int i = 0; i < 4; i++)
#pragma unroll
    for (int j = 0; j < 4; j++) acc[i][j] = zero;

  const int sr = tid >> 2;
  const int sc = (tid & 3) * 8;
  const unsigned short* gA0 = Y + (size_t)(row0 + sr) * DIM + sc;
  const unsigned short* gA1 = gA0 + (size_t)64 * DIM;
  const unsigned short* gB0 = Y + (size_t)(col0 + sr) * DIM + sc;
  const unsigned short* gB1 = gB0 + (size_t)64 * DIM;

  const int fr = lane & 15;
  const int fc = (lane >> 4) * 8;

  for (int k0 = 0; k0 < DIM; k0 += 32) {
    __builtin_amdgcn_global_load_lds(
        (const __attribute__((address_space(1))) void*)(gA0 + k0),
        (__attribute__((address_space(3))) void*)(sA + tid * 8), 16, 0, 0);
    __builtin_amdgcn_global_load_lds(
        (const __attribute__((address_space(1))) void*)(gA1 + k0),
        (__attribute__((address_space(3))) void*)(sA + 2048 + tid * 8), 16, 0, 0);
    __builtin_amdgcn_global_load_lds(
        (const __attribute__((address_space(1))) void*)(gB0 + k0),
        (__attribute__((address_space(3))) void*)(sB + tid * 8), 16, 0, 0);
    __builtin_amdgcn_global_load_lds(
        (const __attribute__((address_space(1))) void*)(gB1 + k0),
        (__attribute__((address_space(3))) void*)(sB + 2048 + tid * 8), 16, 0, 0);
    __syncthreads();

    shortx8 af[4], bf[4];
#pragma unroll
    for (int mi = 0; mi < 4; mi++)
      af[mi] = *(const shortx8*)(sA + (wr * 64 + mi * 16 + fr) * 32 + fc);
#pragma unroll
    for (int ni = 0; ni < 4; ni++)
      bf[ni] = *(const shortx8*)(sB + (wc * 64 + ni * 16 + fr) * 32 + fc);
#pragma unroll
    for (int mi = 0; mi < 4; mi++)
#pragma unroll
      for (int ni = 0; ni < 4; ni++)
        acc[mi][ni] = __builtin_amdgcn_mfma_f32_16x16x32_bf16(af[mi], bf[ni], acc[mi][ni], 0, 0, 0);
    __syncthreads();
  }

  const int cc  = lane & 15;
  const int cr4 = (lane >> 4) * 4;
#pragma unroll
  for (int mi = 0; mi < 4; mi++) {
    const int row = row0 + wr * 64 + mi * 16 + cr4;
#pragma unroll
    for (int ni = 0; ni < 4; ni++) {
      const int col = col0 + wc * 64 + ni * 16 + cc;
      float* dst = S + (size_t)row * NROWS + col;
#pragma unroll
      for (int r = 0; r < 4; r++) dst[(size_t)r * NROWS] = acc[mi][ni][r] * INV_TEMP;
    }
  }
}

__global__ __launch_bounds__(256) void k_rowsum(const float* __restrict__ S,
                                                float* __restrict__ T) {
  const int row = blockIdx.x;
  const float* sr = S + (size_t)row * NROWS;
  float s = 0.f;
  for (int b = threadIdx.x; b < NROWS; b += 256) s += __expf(sr[b]);
#pragma unroll
  for (int off = 32; off > 0; off >>= 1) s += __shfl_down(s, off, 64);
  __shared__ float wsum[4];
  if ((threadIdx.x & 63) == 0) wsum[threadIdx.x >> 6] = s;
  __syncthreads();
  if (threadIdx.x == 0) T[row] = wsum[0] + wsum[1] + wsum[2] + wsum[3];
}

__global__ __launch_bounds__(64) void k_dsum(const float* __restrict__ S,
                                             const float* __restrict__ T,
                                             float* __restrict__ Ds) {
  const int p = blockIdx.x;
  const int k = blockIdx.y;
  const int a = 12 * (p >> 2) + (p & 3);
  const int lane = threadIdx.x;
  const int row = (a + 4 * k) & (NROWS - 1);
  const int m = a >> 2;
  const int c = a & 3;
  const float4* sr4 = (const float4*)(S + (size_t)row * NROWS);
  float s = 0.f;
  {
    float4 v0 = sr4[(m + lane) & 511];
    float4 v1 = sr4[(m + 64 + lane) & 511];
    float e0 = c == 0 ? v0.x : c == 1 ? v0.y : c == 2 ? v0.z : v0.w;
    float e1 = c == 0 ? v1.x : c == 1 ? v1.y : c == 2 ? v1.z : v1.w;
    s += __expf(e0) + __expf(e1);
    if (lane < 32) {
      float4 v2 = sr4[(m + 128 + lane) & 511];
      float e2 = c == 0 ? v2.x : c == 1 ? v2.y : c == 2 ? v2.z : v2.w;
      s += __expf(e2);
    }
  }
#pragma unroll
  for (int off = 32; off > 0; off >>= 1) s += __shfl_down(s, off, 64);
  if (lane == 0) Ds[p * 6 + k] = T[row] - s;
}

__global__ __launch_bounds__(256) void k_final(const float* __restrict__ S,
                                               const float* __restrict__ Ds,
                                               float* __restrict__ out) {
  const int pa[7] = {0, 1, 0, 3, 4, 1, 2};
  const int pb[7] = {1, 2, 3, 4, 5, 4, 5};
  const int idx = blockIdx.x * 256 + threadIdx.x;
  float s = 0.f;
  if (idx < NACT * 7) {
    const int p = idx / 7;
    const int q = idx - p * 7;
    const int a0 = 12 * (p >> 2) + (p & 3);
    const int ra = (a0 + 4 * pa[q]) & (NROWS - 1);
    const int rb = (a0 + 4 * pb[q]) & (NROWS - 1);
    const float num = S[(size_t)ra * NROWS + rb];
    const float en = __expf(num);
    s = __logf(en + Ds[p * 6 + pa[q]]) + __logf(en + Ds[p * 6 + pb[q]]) - 2.f * num;
  }
#pragma unroll
  for (int off = 32; off > 0; off >>= 1) s += __shfl_down(s, off, 64);
  if ((threadIdx.x & 63) == 0) atomicAdd(out, s * (1.0f / (6.0f * 512.0f)));
}

extern "C" void kernel_launch(void* const* d_in, const int* in_sizes, int n_in,
                              void* d_out, int out_size, void* d_ws, size_t ws_size,
                              hipStream_t stream) {
  const float* X = (const float*)d_in[0];
  char* ws = (char*)d_ws;
  float* out = (float*)d_out;

  const size_t pOff = (size_t)32 * 1024 * 1024;
  const size_t needA = pOff + 8192 + 256;

  if (ws_size >= needA) {
    unsigned char* Yq = (unsigned char*)ws;                                 // 8 MB fp8
    unsigned short* S16 = (unsigned short*)(ws + (size_t)16 * 1024 * 1024); // 8 MB fp16
    float* T  = (float*)(ws + pOff);
    hipLaunchKernelGGL(k_normconv_fp8, dim3(NROWS), dim3(256), 0, stream, X, Yq, T, out);
    hipLaunchKernelGGL(k_gemm_full, dim3(NTILE64), dim3(256), 0, stream, Yq, S16, T);
    hipLaunchKernelGGL(k_tail, dim3(NACT), dim3(384), 0, stream, S16, T, out);
  } else {
    unsigned short* Y = (unsigned short*)ws;                      // 16 MB bf16
    float* S = (float*)(ws + (size_t)16 * 1024 * 1024);           // 16 MB fp32
    float* T  = (float*)(ws + pOff);
    float* Ds = (float*)(ws + pOff + 8192);
    hipMemsetAsync(out, 0, sizeof(float), stream);
    hipLaunchKernelGGL(k_normconv, dim3(NROWS), dim3(256), 0, stream, X, Y);
    hipLaunchKernelGGL(k_gemm, dim3(16, 16), dim3(256), 0, stream, Y, S);
    hipLaunchKernelGGL(k_rowsum, dim3(NROWS), dim3(256), 0, stream, S, T);
    hipLaunchKernelGGL(k_dsum, dim3(NACT, 6), dim3(64), 0, stream, S, T, Ds);
    hipLaunchKernelGGL(k_final, dim3((NACT * 7 + 255) / 256), dim3(256), 0, stream, S, Ds, out);
  }
}

// Round 5
// 107.651 us; speedup vs baseline: 2.0044x; 1.0100x over previous
//
#include <hip/hip_runtime.h>
#include <hip/hip_bf16.h>
#include <stdint.h>

#define NROWS 2048
#define DIM   4096
#define NACT  684
#define INV_TEMP 10.0f
#define NPANEL 32        // 2048/64 row panels
#define NTILE64 528      // 32*33/2 upper-triangle 64x64 tiles
#define NK 64            // DIM / 64 K-steps
#define FP8_SCALE 16.0f  // Y stored as fp8(y*16); dot = 256*cos
#define OUT_SCALE (INV_TEMP / 256.0f)

// s_waitcnt immediates (gfx9/CDNA: vmcnt[3:0]@0, expcnt@4, lgkmcnt@8, vmcnt[5:4]@14)
#define WAITCNT_VM0   0x0F70
#define WAITCNT_VM4   0x0F74
#define WAITCNT_VM8   0x0F78

typedef __attribute__((ext_vector_type(4))) float floatx4;
typedef __attribute__((ext_vector_type(16))) float floatx16;
typedef __attribute__((ext_vector_type(4))) int intx4;
typedef __attribute__((ext_vector_type(8))) int intx8;
typedef __attribute__((ext_vector_type(8))) short shortx8;
typedef __attribute__((ext_vector_type(8))) unsigned short ushortx8;

static __device__ __forceinline__ unsigned short f32_to_bf16(float f) {
  union { float f; unsigned int u; } v; v.f = f;
  unsigned int u = v.u;
  unsigned int r = u + 0x7fffu + ((u >> 16) & 1u);
  return (unsigned short)(r >> 16);
}
static __device__ __forceinline__ float bf16_to_f32(unsigned short u) {
  union { unsigned int u; float f; } v; v.u = ((unsigned int)u) << 16;
  return v.f;
}
static __device__ __forceinline__ unsigned short f32_to_f16(float f) {
  _Float16 h = (_Float16)f;
  union { _Float16 h; unsigned short u; } v; v.h = h;
  return v.u;
}
static __device__ __forceinline__ float f16_to_f32(unsigned short u) {
  union { unsigned short u; _Float16 h; } v; v.u = u;
  return (float)v.h;
}

// ------- Kernel 1A: per-row L2 norm + fp8 e4m3 convert (y*16); zeroes T/out -------
__global__ __launch_bounds__(256) void k_normconv_fp8(const float* __restrict__ X,
                                                      unsigned char* __restrict__ Yq,
                                                      float* __restrict__ T,
                                                      float* __restrict__ out) {
  const int row = blockIdx.x;
  if (threadIdx.x == 0) T[row] = 0.f;             // replaces hipMemsetAsync(T)
  if (row == 0 && threadIdx.x == 64) *out = 0.f;  // replaces hipMemsetAsync(out)
  const float4* xr = (const float4*)(X + (size_t)row * DIM);
  float4 v[4];
  float s = 0.f;
#pragma unroll
  for (int t = 0; t < 4; t++) {
    float4 w = xr[threadIdx.x + t * 256];
    v[t] = w;
    s += w.x * w.x + w.y * w.y + w.z * w.z + w.w * w.w;
  }
#pragma unroll
  for (int off = 32; off > 0; off >>= 1) s += __shfl_down(s, off, 64);
  __shared__ float wsum[4];
  if ((threadIdx.x & 63) == 0) wsum[threadIdx.x >> 6] = s;
  __syncthreads();
  const float total = wsum[0] + wsum[1] + wsum[2] + wsum[3];
  const float sc = FP8_SCALE / fmaxf(sqrtf(total), 1e-30f);
  unsigned int* yr = (unsigned int*)(Yq + (size_t)row * DIM);
#pragma unroll
  for (int t = 0; t < 4; t++) {
    float4 w = v[t];
    unsigned int r0 = __builtin_amdgcn_cvt_pk_fp8_f32(w.x * sc, w.y * sc, 0, false);
    r0 = __builtin_amdgcn_cvt_pk_fp8_f32(w.z * sc, w.w * sc, r0, true);
    yr[threadIdx.x + t * 256] = r0;
  }
}

// ------- Kernel 2A: full-K 64x64-tile MX-fp8 GEMM with fused S/T epilogue -------
// 528 tiles, each block does K=4096. 6-stage ring (8 KB/stage = one 64-B K-step),
// TWO K-steps (2 MFMA) per barrier-pair -> 64 barrier-phases instead of 128, and
// prefetch distance 4 K-steps (2 phases, covers L3 latency). Counted vmcnt:
// steady state 12 loads outstanding, vmcnt(8) drains exactly the consumed pair.
// s_setprio(1) around the MFMA cluster (independent blocks per CU -> role diversity).
__global__ __launch_bounds__(256) void k_gemm_full(const unsigned char* __restrict__ Yq,
                                                   unsigned short* __restrict__ S,
                                                   float* __restrict__ T) {
  __shared__ __attribute__((aligned(16))) unsigned char lds[6 * 8192];
  // bijective XCD-aware swizzle (528 = 8*66): consecutive logical tiles share an XCD.
  const int bid0 = blockIdx.x;
  const int t = (bid0 & 7) * 66 + (bid0 >> 3);
  int ti = 0, rem = t;
  while (rem >= NPANEL - ti) { rem -= NPANEL - ti; ti++; }
  const int tj = ti + rem;
  const int gr = ti * 64;
  const int gc = tj * 64;

  const int tid  = threadIdx.x;
  const int lane = tid & 63;
  const int wave = tid >> 6;
  const int wr = wave >> 1;
  const int wc = wave & 1;

  floatx16 acc = {0.f, 0.f, 0.f, 0.f, 0.f, 0.f, 0.f, 0.f,
                  0.f, 0.f, 0.f, 0.f, 0.f, 0.f, 0.f, 0.f};

  // staging: thread t covers 16 B: row r2 = t>>2 (0..63), chunk c16 = t&3.
  // Source column pre-swizzled (linear LDS dest + inverse-swizzled source + swizzled read).
  const int r2  = tid >> 2;
  const int c16 = tid & 3;
  const unsigned int swst = (unsigned)(((r2 >> 1) & 3) << 4);
  const unsigned int colst = ((unsigned)(c16 << 4)) ^ swst;
  const unsigned char* gA = Yq + (size_t)(gr + r2) * DIM + colst;
  const unsigned char* gB = Yq + (size_t)(gc + r2) * DIM + colst;

#define ISSUE(st, koff)                                                                  \
  do {                                                                                   \
    __builtin_amdgcn_global_load_lds(                                                    \
        (const __attribute__((address_space(1))) void*)(gA + (koff)),                    \
        (__attribute__((address_space(3))) void*)(lds + (st) * 8192 + tid * 16),         \
        16, 0, 0);                                                                       \
    __builtin_amdgcn_global_load_lds(                                                    \
        (const __attribute__((address_space(1))) void*)(gB + (koff)),                    \
        (__attribute__((address_space(3))) void*)(lds + (st) * 8192 + 4096 + tid * 16),  \
        16, 0, 0);                                                                       \
  } while (0)

  // Fragment read: wave (wr,wc) computes quadrant rows wr*32.., cols (B-rows) wc*32..
#define COMPUTE(st)                                                                      \
  do {                                                                                   \
    const unsigned char* bA = lds + (st) * 8192;                                         \
    const unsigned char* bB = bA + 4096;                                                 \
    const unsigned int c0 = (unsigned)((lane >> 5) << 5);                                \
    const int rA = wr * 32 + (lane & 31);                                                \
    const int rB = wc * 32 + (lane & 31);                                                \
    const unsigned int swA = (unsigned)(((rA >> 1) & 3) << 4);                           \
    const unsigned int swB = (unsigned)(((rB >> 1) & 3) << 4);                           \
    const unsigned char* baseA = bA + rA * 64;                                           \
    const unsigned char* baseB = bB + rB * 64;                                           \
    intx4 alo = *(const intx4*)(baseA + (c0 ^ swA));                                     \
    intx4 ahi = *(const intx4*)(baseA + ((c0 ^ swA) ^ 16u));                             \
    intx4 blo = *(const intx4*)(baseB + (c0 ^ swB));                                     \
    intx4 bhi = *(const intx4*)(baseB + ((c0 ^ swB) ^ 16u));                             \
    intx8 af, bf;                                                                        \
    af[0] = alo[0]; af[1] = alo[1]; af[2] = alo[2]; af[3] = alo[3];                      \
    af[4] = ahi[0]; af[5] = ahi[1]; af[6] = ahi[2]; af[7] = ahi[3];                      \
    bf[0] = blo[0]; bf[1] = blo[1]; bf[2] = blo[2]; bf[3] = blo[3];                      \
    bf[4] = bhi[0]; bf[5] = bhi[1]; bf[6] = bhi[2]; bf[7] = bhi[3];                      \
    acc = __builtin_amdgcn_mfma_scale_f32_32x32x64_f8f6f4(                               \
        af, bf, acc, 0, 0, 0, 0x7F7F7F7F, 0, 0x7F7F7F7F);                                \
  } while (0)

  // Prologue: 4 K-steps in flight (8 loads).
  ISSUE(0, 0);
  ISSUE(1, 64);
  ISSUE(2, 128);
  ISSUE(3, 192);
#pragma unroll
  for (int p = 0; p < 32; p++) {
    const int a = (2 * p) % 6;            // compile-time after full unroll
    if (p < 30) {
      const int na = (2 * p + 4) % 6;
      ISSUE(na, (2 * p + 4) * 64);
      ISSUE(na + 1, (2 * p + 5) * 64);
      __builtin_amdgcn_s_waitcnt(WAITCNT_VM8);   // 12 outstanding -> drain oldest pair
    } else if (p == 30) {
      __builtin_amdgcn_s_waitcnt(WAITCNT_VM4);
    } else {
      __builtin_amdgcn_s_waitcnt(WAITCNT_VM0);
    }
    __builtin_amdgcn_sched_barrier(0);
    __builtin_amdgcn_s_barrier();
    __builtin_amdgcn_s_setprio(1);
    COMPUTE(a);
    COMPUTE(a + 1);
    __builtin_amdgcn_s_setprio(0);
    if (p < 31) {
      __builtin_amdgcn_s_barrier();
      __builtin_amdgcn_sched_barrier(0);
    }
  }

#undef ISSUE
#undef COMPUTE

  // ---- fused epilogue (LDS reused; all staging reads are done) ----
  // 32x32 C/D layout: col = lane&31, row = (reg&3) + 8*(reg>>2) + 4*(lane>>5).
  unsigned short* tile16 = (unsigned short*)lds;        // [64][66] f16   (8448 B)
  float* tileE   = (float*)(lds + 8448);                // [64][65] float (16640 B)
  float* colpart = (float*)(lds + 25088);               // [2][64]        (512 B)
  __syncthreads();

  {
    const int col = wc * 32 + (lane & 31);
    float evsum = 0.f;
#pragma unroll
    for (int i = 0; i < 16; i++) {
      const int row = wr * 32 + (i & 3) + 8 * (i >> 2) + 4 * (lane >> 5);
      const float v = acc[i] * OUT_SCALE;
      const float ev = __expf(v);
      tile16[row * 66 + col] = f32_to_f16(v);
      tileE[row * 65 + col] = ev;
      evsum += ev;
    }
    evsum += __shfl_xor(evsum, 32, 64);
    if (lane < 32) colpart[wr * 64 + col] = evsum;   // wave-unique slot, no atomic
  }
  __syncthreads();

  // col sums -> T[gc+c]  (symmetry: column sum == mirrored row sum)
  if (tid < 64) atomicAdd(&T[gc + tid], colpart[tid] + colpart[64 + tid]);

  // main tile write: S[gr+r][gc .. gc+63], coalesced
  {
    const int r = tid >> 2, seg = tid & 3;
    const unsigned int* q = (const unsigned int*)tile16 + (r * 33 + seg * 8);
    uint4 w0, w1;
    w0.x = q[0]; w0.y = q[1]; w0.z = q[2]; w0.w = q[3];
    w1.x = q[4]; w1.y = q[5]; w1.z = q[6]; w1.w = q[7];
    uint4* dst = (uint4*)(S + (size_t)(gr + r) * NROWS + gc + seg * 16);
    dst[0] = w0; dst[1] = w1;
  }

  if (ti != tj) {
    // row sums -> T[gr+r]
    if (tid < 64) {
      float rs = 0.f;
#pragma unroll 8
      for (int c = 0; c < 64; c++) rs += tileE[tid * 65 + c];
      atomicAdd(&T[gr + tid], rs);
    }
    // mirror write: S[gc+c][gr .. gr+63]
    {
      const int c = tid >> 2, seg = tid & 3;
      unsigned short tmp[16];
#pragma unroll
      for (int k = 0; k < 16; k++) tmp[k] = tile16[(seg * 16 + k) * 66 + c];
      uint4 w0, w1;
      w0.x = (unsigned int)tmp[0]  | ((unsigned int)tmp[1]  << 16);
      w0.y = (unsigned int)tmp[2]  | ((unsigned int)tmp[3]  << 16);
      w0.z = (unsigned int)tmp[4]  | ((unsigned int)tmp[5]  << 16);
      w0.w = (unsigned int)tmp[6]  | ((unsigned int)tmp[7]  << 16);
      w1.x = (unsigned int)tmp[8]  | ((unsigned int)tmp[9]  << 16);
      w1.y = (unsigned int)tmp[10] | ((unsigned int)tmp[11] << 16);
      w1.z = (unsigned int)tmp[12] | ((unsigned int)tmp[13] << 16);
      w1.w = (unsigned int)tmp[14] | ((unsigned int)tmp[15] << 16);
      uint4* dst = (uint4*)(S + (size_t)(gc + c) * NROWS + gr + seg * 16);
      dst[0] = w0; dst[1] = w1;
    }
  }
}

// ---- Kernel 3A: fused Dsum + pair losses. Block per p; 6 waves do the 6 Dsum gathers,
// then 7 lanes of wave 0 do the pair terms from LDS. One global atomic per block. ----
__global__ __launch_bounds__(384) void k_tail(const unsigned short* __restrict__ S,
                                              const float* __restrict__ T,
                                              float* __restrict__ out) {
  __shared__ float ds_s[6];
  const int p = blockIdx.x;
  const int a = 12 * (p >> 2) + (p & 3);
  const int tid = threadIdx.x;
  const int k = tid >> 6;            // 0..5
  const int lane = tid & 63;
  const int row = (a + 4 * k) & (NROWS - 1);
  const int m = a >> 2;
  const int c = a & 3;
  const uint2* sr = (const uint2*)(S + (size_t)row * NROWS);
  float s = 0.f;
  {
    uint2 v0 = sr[(m + lane) & 511];
    uint2 v1 = sr[(m + 64 + lane) & 511];
    unsigned short e0 = (c < 2) ? (unsigned short)(v0.x >> (16 * c))
                                : (unsigned short)(v0.y >> (16 * (c - 2)));
    unsigned short e1 = (c < 2) ? (unsigned short)(v1.x >> (16 * c))
                                : (unsigned short)(v1.y >> (16 * (c - 2)));
    s += __expf(f16_to_f32(e0)) + __expf(f16_to_f32(e1));
    if (lane < 32) {
      uint2 v2 = sr[(m + 128 + lane) & 511];
      unsigned short e2 = (c < 2) ? (unsigned short)(v2.x >> (16 * c))
                                  : (unsigned short)(v2.y >> (16 * (c - 2)));
      s += __expf(f16_to_f32(e2));
    }
  }
#pragma unroll
  for (int off = 32; off > 0; off >>= 1) s += __shfl_down(s, off, 64);
  if (lane == 0) ds_s[k] = T[row] - s;
  __syncthreads();

  float r = 0.f;
  if (tid < 7) {
    const int pa[7] = {0, 1, 0, 3, 4, 1, 2};
    const int pb[7] = {1, 2, 3, 4, 5, 4, 5};
    const int ra = (a + 4 * pa[tid]) & (NROWS - 1);
    const int rb = (a + 4 * pb[tid]) & (NROWS - 1);
    const float num = f16_to_f32(S[(size_t)ra * NROWS + rb]);
    const float en = __expf(num);
    r = __logf(en + ds_s[pa[tid]]) + __logf(en + ds_s[pb[tid]]) - 2.f * num;
  }
  if (tid < 64) {
    r += __shfl_down(r, 4, 64);
    r += __shfl_down(r, 2, 64);
    r += __shfl_down(r, 1, 64);
    if (tid == 0) atomicAdd(out, r * (1.0f / (6.0f * 512.0f)));
  }
}

// ------------- Path B kernels (fallback when ws is small; fp32 S) -------------
__global__ __launch_bounds__(256) void k_normconv(const float* __restrict__ X,
                                                  unsigned short* __restrict__ Y) {
  const int row = blockIdx.x;
  const float4* xr = (const float4*)(X + (size_t)row * DIM);
  float4 v[4];
  float s = 0.f;
#pragma unroll
  for (int t = 0; t < 4; t++) {
    float4 w = xr[threadIdx.x + t * 256];
    v[t] = w;
    s += w.x * w.x + w.y * w.y + w.z * w.z + w.w * w.w;
  }
#pragma unroll
  for (int off = 32; off > 0; off >>= 1) s += __shfl_down(s, off, 64);
  __shared__ float wsum[4];
  if ((threadIdx.x & 63) == 0) wsum[threadIdx.x >> 6] = s;
  __syncthreads();
  const float total = wsum[0] + wsum[1] + wsum[2] + wsum[3];
  const float inv = 1.0f / fmaxf(sqrtf(total), 1e-30f);
  ushort4* yr = (ushort4*)(Y + (size_t)row * DIM);
#pragma unroll
  for (int t = 0; t < 4; t++) {
    float4 w = v[t];
    ushort4 o;
    o.x = f32_to_bf16(w.x * inv);
    o.y = f32_to_bf16(w.y * inv);
    o.z = f32_to_bf16(w.z * inv);
    o.w = f32_to_bf16(w.w * inv);
    yr[threadIdx.x + t * 256] = o;
  }
}

__global__ __launch_bounds__(256) void k_gemm(const unsigned short* __restrict__ Y,
                                              float* __restrict__ S) {
  __shared__ __attribute__((aligned(16))) unsigned short sA[128 * 32];
  __shared__ __attribute__((aligned(16))) unsigned short sB[128 * 32];
  const int tid  = threadIdx.x;
  const int lane = tid & 63;
  const int wave = tid >> 6;
  const int wr = wave >> 1;
  const int wc = wave & 1;
  const int row0 = blockIdx.y * 128;
  const int col0 = blockIdx.x * 128;

  floatx4 zero = {0.f, 0.f, 0.f, 0.f};
  floatx4 acc[4][4];
#pragma unroll
  for (int i = 0; i < 4; i++)
#pragma unroll
    for (int j = 0; j < 4; j++) acc[i][j] = zero;

  const int sr = tid >> 2;
  const int sc = (tid & 3) * 8;
  const unsigned short* gA0 = Y + (size_t)(row0 + sr) * DIM + sc;
  const unsigned short* gA1 = gA0 + (size_t)64 * DIM;
  const unsigned short* gB0 = Y + (size_t)(col0 + sr) * DIM + sc;
  const unsigned short* gB1 = gB0 + (size_t)64 * DIM;

  const int fr = lane & 15;
  const int fc = (lane >> 4) * 8;

  for (int k0 = 0; k0 < DIM; k0 += 32) {
    __builtin_amdgcn_global_load_lds(
        (const __attribute__((address_space(1))) void*)(gA0 + k0),
        (__attribute__((address_space(3))) void*)(sA + tid * 8), 16, 0, 0);
    __builtin_amdgcn_global_load_lds(
        (const __attribute__((address_space(1))) void*)(gA1 + k0),
        (__attribute__((address_space(3))) void*)(sA + 2048 + tid * 8), 16, 0, 0);
    __builtin_amdgcn_global_load_lds(
        (const __attribute__((address_space(1))) void*)(gB0 + k0),
        (__attribute__((address_space(3))) void*)(sB + tid * 8), 16, 0, 0);
    __builtin_amdgcn_global_load_lds(
        (const __attribute__((address_space(1))) void*)(gB1 + k0),
        (__attribute__((address_space(3))) void*)(sB + 2048 + tid * 8), 16, 0, 0);
    __syncthreads();

    shortx8 af[4], bf[4];
#pragma unroll
    for (int mi = 0; mi < 4; mi++)
      af[mi] = *(const shortx8*)(sA + (wr * 64 + mi * 16 + fr) * 32 + fc);
#pragma unroll
    for (int ni = 0; ni < 4; ni++)
      bf[ni] = *(const shortx8*)(sB + (wc * 64 + ni * 16 + fr) * 32 + fc);
#pragma unroll
    for (int mi = 0; mi < 4; mi++)
#pragma unroll
      for (int ni = 0; ni < 4; ni++)
        acc[mi][ni] = __builtin_amdgcn_mfma_f32_16x16x32_bf16(af[mi], bf[ni], acc[mi][ni], 0, 0, 0);
    __syncthreads();
  }

  const int cc  = lane & 15;
  const int cr4 = (lane >> 4) * 4;
#pragma unroll
  for (int mi = 0; mi < 4; mi++) {
    const int row = row0 + wr * 64 + mi * 16 + cr4;
#pragma unroll
    for (int ni = 0; ni < 4; ni++) {
      const int col = col0 + wc * 64 + ni * 16 + cc;
      float* dst = S + (size_t)row * NROWS + col;
#pragma unroll
      for (int r = 0; r < 4; r++) dst[(size_t)r * NROWS] = acc[mi][ni][r] * INV_TEMP;
    }
  }
}

__global__ __launch_bounds__(256) void k_rowsum(const float* __restrict__ S,
                                                float* __restrict__ T) {
  const int row = blockIdx.x;
  const float* sr = S + (size_t)row * NROWS;
  float s = 0.f;
  for (int b = threadIdx.x; b < NROWS; b += 256) s += __expf(sr[b]);
#pragma unroll
  for (int off = 32; off > 0; off >>= 1) s += __shfl_down(s, off, 64);
  __shared__ float wsum[4];
  if ((threadIdx.x & 63) == 0) wsum[threadIdx.x >> 6] = s;
  __syncthreads();
  if (threadIdx.x == 0) T[row] = wsum[0] + wsum[1] + wsum[2] + wsum[3];
}

__global__ __launch_bounds__(64) void k_dsum(const float* __restrict__ S,
                                             const float* __restrict__ T,
                                             float* __restrict__ Ds) {
  const int p = blockIdx.x;
  const int k = blockIdx.y;
  const int a = 12 * (p >> 2) + (p & 3);
  const int lane = threadIdx.x;
  const int row = (a + 4 * k) & (NROWS - 1);
  const int m = a >> 2;
  const int c = a & 3;
  const float4* sr4 = (const float4*)(S + (size_t)row * NROWS);
  float s = 0.f;
  {
    float4 v0 = sr4[(m + lane) & 511];
    float4 v1 = sr4[(m + 64 + lane) & 511];
    float e0 = c == 0 ? v0.x : c == 1 ? v0.y : c == 2 ? v0.z : v0.w;
    float e1 = c == 0 ? v1.x : c == 1 ? v1.y : c == 2 ? v1.z : v1.w;
    s += __expf(e0) + __expf(e1);
    if (lane < 32) {
      float4 v2 = sr4[(m + 128 + lane) & 511];
      float e2 = c == 0 ? v2.x : c == 1 ? v2.y : c == 2 ? v2.z : v2.w;
      s += __expf(e2);
    }
  }
#pragma unroll
  for (int off = 32; off > 0; off >>= 1) s += __shfl_down(s, off, 64);
  if (lane == 0) Ds[p * 6 + k] = T[row] - s;
}

__global__ __launch_bounds__(256) void k_final(const float* __restrict__ S,
                                               const float* __restrict__ Ds,
                                               float* __restrict__ out) {
  const int pa[7] = {0, 1, 0, 3, 4, 1, 2};
  const int pb[7] = {1, 2, 3, 4, 5, 4, 5};
  const int idx = blockIdx.x * 256 + threadIdx.x;
  float s = 0.f;
  if (idx < NACT * 7) {
    const int p = idx / 7;
    const int q = idx - p * 7;
    const int a0 = 12 * (p >> 2) + (p & 3);
    const int ra = (a0 + 4 * pa[q]) & (NROWS - 1);
    const int rb = (a0 + 4 * pb[q]) & (NROWS - 1);
    const float num = S[(size_t)ra * NROWS + rb];
    const float en = __expf(num);
    s = __logf(en + Ds[p * 6 + pa[q]]) + __logf(en + Ds[p * 6 + pb[q]]) - 2.f * num;
  }
#pragma unroll
  for (int off = 32; off > 0; off >>= 1) s += __shfl_down(s, off, 64);
  if ((threadIdx.x & 63) == 0) atomicAdd(out, s * (1.0f / (6.0f * 512.0f)));
}

extern "C" void kernel_launch(void* const* d_in, const int* in_sizes, int n_in,
                              void* d_out, int out_size, void* d_ws, size_t ws_size,
                              hipStream_t stream) {
  const float* X = (const float*)d_in[0];
  char* ws = (char*)d_ws;
  float* out = (float*)d_out;

  const size_t pOff = (size_t)32 * 1024 * 1024;
  const size_t needA = pOff + 8192 + 256;

  if (ws_size >= needA) {
    unsigned char* Yq = (unsigned char*)ws;                                 // 8 MB fp8
    unsigned short* S16 = (unsigned short*)(ws + (size_t)16 * 1024 * 1024); // 8 MB fp16
    float* T  = (float*)(ws + pOff);
    hipLaunchKernelGGL(k_normconv_fp8, dim3(NROWS), dim3(256), 0, stream, X, Yq, T, out);
    hipLaunchKernelGGL(k_gemm_full, dim3(NTILE64), dim3(256), 0, stream, Yq, S16, T);
    hipLaunchKernelGGL(k_tail, dim3(NACT), dim3(384), 0, stream, S16, T, out);
  } else {
    unsigned short* Y = (unsigned short*)ws;                      // 16 MB bf16
    float* S = (float*)(ws + (size_t)16 * 1024 * 1024);           // 16 MB fp32
    float* T  = (float*)(ws + pOff);
    float* Ds = (float*)(ws + pOff + 8192);
    hipMemsetAsync(out, 0, sizeof(float), stream);
    hipLaunchKernelGGL(k_normconv, dim3(NROWS), dim3(256), 0, stream, X, Y);
    hipLaunchKernelGGL(k_gemm, dim3(16, 16), dim3(256), 0, stream, Y, S);
    hipLaunchKernelGGL(k_rowsum, dim3(NROWS), dim3(256), 0, stream, S, T);
    hipLaunchKernelGGL(k_dsum, dim3(NACT, 6), dim3(64), 0, stream, S, T, Ds);
    hipLaunchKernelGGL(k_final, dim3((NACT * 7 + 255) / 256), dim3(256), 0, stream, S, Ds, out);
  }
}

// Round 6
// 105.174 us; speedup vs baseline: 2.0516x; 1.0235x over previous
//
#include <hip/hip_runtime.h>
#include <hip/hip_bf16.h>
#include <stdint.h>

#define NROWS 2048
#define DIM   4096
#define NACT  684
#define INV_TEMP 10.0f
#define NPANEL 32        // 2048/64 row panels
#define NTILE64 528      // 32*33/2 upper-triangle 64x64 tiles
#define NK 64            // DIM / 64 K-steps
#define FP8_SCALE 16.0f  // Y stored as fp8(y*16); dot = 256*cos
#define OUT_SCALE (INV_TEMP / 256.0f)

// s_waitcnt immediates (gfx9/CDNA: vmcnt[3:0]@0, expcnt@4, lgkmcnt@8, vmcnt[5:4]@14)
#define WAITCNT_VM0   0x0F70
#define WAITCNT_VM4   0x0F74
#define WAITCNT_VM8   0x0F78

typedef __attribute__((ext_vector_type(4))) float floatx4;
typedef __attribute__((ext_vector_type(16))) float floatx16;
typedef __attribute__((ext_vector_type(4))) int intx4;
typedef __attribute__((ext_vector_type(8))) int intx8;
typedef __attribute__((ext_vector_type(8))) short shortx8;
typedef __attribute__((ext_vector_type(8))) unsigned short ushortx8;

static __device__ __forceinline__ unsigned short f32_to_bf16(float f) {
  union { float f; unsigned int u; } v; v.f = f;
  unsigned int u = v.u;
  unsigned int r = u + 0x7fffu + ((u >> 16) & 1u);
  return (unsigned short)(r >> 16);
}
static __device__ __forceinline__ float bf16_to_f32(unsigned short u) {
  union { unsigned int u; float f; } v; v.u = ((unsigned int)u) << 16;
  return v.f;
}
static __device__ __forceinline__ unsigned short f32_to_f16(float f) {
  _Float16 h = (_Float16)f;
  union { _Float16 h; unsigned short u; } v; v.h = h;
  return v.u;
}
static __device__ __forceinline__ float f16_to_f32(unsigned short u) {
  union { unsigned short u; _Float16 h; } v; v.u = u;
  return (float)v.h;
}

// Pair tables: pa/pb per q; col-row delta = 4*(pb-pa) in {4,12}.
// delta==4  -> q in {0,1,3,4} with pa {0,1,3,4}
// delta==12 -> q in {2,5,6}   with pa {0,1,2}
static __device__ __forceinline__ void num_store(float* __restrict__ NUM, int R, int delta,
                                                 float v) {
  if (delta == 4) {
    const int qs[4]  = {0, 1, 3, 4};
    const int pas[4] = {0, 1, 3, 4};
#pragma unroll
    for (int u = 0; u < 4; u++) {
      const int aa = (R - 4 * pas[u]) & (NROWS - 1);
      if (aa % 12 < 4) NUM[((aa / 12) * 4 + (aa % 12)) * 7 + qs[u]] = v;
    }
  } else {
    const int qs[3]  = {2, 5, 6};
    const int pas[3] = {0, 1, 2};
#pragma unroll
    for (int u = 0; u < 3; u++) {
      const int aa = (R - 4 * pas[u]) & (NROWS - 1);
      if (aa % 12 < 4) NUM[((aa / 12) * 4 + (aa % 12)) * 7 + qs[u]] = v;
    }
  }
}

// ------- Kernel 1A: per-row L2 norm + fp8 e4m3 convert (y*16); zeroes T/WS/out -------
__global__ __launch_bounds__(256) void k_normconv_fp8(const float* __restrict__ X,
                                                      unsigned char* __restrict__ Yq,
                                                      float* __restrict__ T,
                                                      float* __restrict__ WS,
                                                      float* __restrict__ out) {
  const int row = blockIdx.x;
  if (threadIdx.x == 0) T[row] = 0.f;             // replaces hipMemsetAsync(T)
  if (row == 0 && threadIdx.x == 64) *out = 0.f;  // replaces hipMemsetAsync(out)
  if (row < NACT && threadIdx.x >= 192 && threadIdx.x < 198)
    WS[row * 6 + (threadIdx.x - 192)] = 0.f;      // zero window-sum accumulators
  const float4* xr = (const float4*)(X + (size_t)row * DIM);
  float4 v[4];
  float s = 0.f;
#pragma unroll
  for (int t = 0; t < 4; t++) {
    float4 w = xr[threadIdx.x + t * 256];
    v[t] = w;
    s += w.x * w.x + w.y * w.y + w.z * w.z + w.w * w.w;
  }
#pragma unroll
  for (int off = 32; off > 0; off >>= 1) s += __shfl_down(s, off, 64);
  __shared__ float wsum[4];
  if ((threadIdx.x & 63) == 0) wsum[threadIdx.x >> 6] = s;
  __syncthreads();
  const float total = wsum[0] + wsum[1] + wsum[2] + wsum[3];
  const float sc = FP8_SCALE / fmaxf(sqrtf(total), 1e-30f);
  unsigned int* yr = (unsigned int*)(Yq + (size_t)row * DIM);
#pragma unroll
  for (int t = 0; t < 4; t++) {
    float4 w = v[t];
    unsigned int r0 = __builtin_amdgcn_cvt_pk_fp8_f32(w.x * sc, w.y * sc, 0, false);
    r0 = __builtin_amdgcn_cvt_pk_fp8_f32(w.z * sc, w.w * sc, r0, true);
    yr[threadIdx.x + t * 256] = r0;
  }
}

// ------- Kernel 2A: full-K 64x64-tile MX-fp8 GEMM, FULLY fused epilogue -------
// Same proven 6-stage ring / counted-vmcnt / setprio K-loop as round 5. The epilogue now
// produces EVERYTHING downstream needs directly from the in-LDS E tile:
//   - T row/col exp-sums (as before),
//   - WS[p*6+k] window sums (Dsum = T - WS), via cyclic-range intersection per tile,
//   - NUM[p*7+q] pair numerators (entries at col-row = 4 or 12 mod 2048).
// No S16 matrix is materialized at all; the 684-block gather/atomic tail is replaced by
// a 19-block finisher.
__global__ __launch_bounds__(256) void k_gemm_full(const unsigned char* __restrict__ Yq,
                                                   float* __restrict__ T,
                                                   float* __restrict__ WS,
                                                   float* __restrict__ NUM) {
  __shared__ __attribute__((aligned(16))) unsigned char lds[6 * 8192];
  // bijective XCD-aware swizzle (528 = 8*66): consecutive logical tiles share an XCD.
  const int bid0 = blockIdx.x;
  const int t = (bid0 & 7) * 66 + (bid0 >> 3);
  int ti = 0, rem = t;
  while (rem >= NPANEL - ti) { rem -= NPANEL - ti; ti++; }
  const int tj = ti + rem;
  const int gr = ti * 64;
  const int gc = tj * 64;

  const int tid  = threadIdx.x;
  const int lane = tid & 63;
  const int wave = tid >> 6;
  const int wr = wave >> 1;
  const int wc = wave & 1;

  floatx16 acc = {0.f, 0.f, 0.f, 0.f, 0.f, 0.f, 0.f, 0.f,
                  0.f, 0.f, 0.f, 0.f, 0.f, 0.f, 0.f, 0.f};

  // staging: thread t covers 16 B: row r2 = t>>2 (0..63), chunk c16 = t&3.
  // Source column pre-swizzled (linear LDS dest + inverse-swizzled source + swizzled read).
  const int r2  = tid >> 2;
  const int c16 = tid & 3;
  const unsigned int swst = (unsigned)(((r2 >> 1) & 3) << 4);
  const unsigned int colst = ((unsigned)(c16 << 4)) ^ swst;
  const unsigned char* gA = Yq + (size_t)(gr + r2) * DIM + colst;
  const unsigned char* gB = Yq + (size_t)(gc + r2) * DIM + colst;

#define ISSUE(st, koff)                                                                  \
  do {                                                                                   \
    __builtin_amdgcn_global_load_lds(                                                    \
        (const __attribute__((address_space(1))) void*)(gA + (koff)),                    \
        (__attribute__((address_space(3))) void*)(lds + (st) * 8192 + tid * 16),         \
        16, 0, 0);                                                                       \
    __builtin_amdgcn_global_load_lds(                                                    \
        (const __attribute__((address_space(1))) void*)(gB + (koff)),                    \
        (__attribute__((address_space(3))) void*)(lds + (st) * 8192 + 4096 + tid * 16),  \
        16, 0, 0);                                                                       \
  } while (0)

#define COMPUTE(st)                                                                      \
  do {                                                                                   \
    const unsigned char* bA = lds + (st) * 8192;                                         \
    const unsigned char* bB = bA + 4096;                                                 \
    const unsigned int c0 = (unsigned)((lane >> 5) << 5);                                \
    const int rA = wr * 32 + (lane & 31);                                                \
    const int rB = wc * 32 + (lane & 31);                                                \
    const unsigned int swA = (unsigned)(((rA >> 1) & 3) << 4);                           \
    const unsigned int swB = (unsigned)(((rB >> 1) & 3) << 4);                           \
    const unsigned char* baseA = bA + rA * 64;                                           \
    const unsigned char* baseB = bB + rB * 64;                                           \
    intx4 alo = *(const intx4*)(baseA + (c0 ^ swA));                                     \
    intx4 ahi = *(const intx4*)(baseA + ((c0 ^ swA) ^ 16u));                             \
    intx4 blo = *(const intx4*)(baseB + (c0 ^ swB));                                     \
    intx4 bhi = *(const intx4*)(baseB + ((c0 ^ swB) ^ 16u));                             \
    intx8 af, bf;                                                                        \
    af[0] = alo[0]; af[1] = alo[1]; af[2] = alo[2]; af[3] = alo[3];                      \
    af[4] = ahi[0]; af[5] = ahi[1]; af[6] = ahi[2]; af[7] = ahi[3];                      \
    bf[0] = blo[0]; bf[1] = blo[1]; bf[2] = blo[2]; bf[3] = blo[3];                      \
    bf[4] = bhi[0]; bf[5] = bhi[1]; bf[6] = bhi[2]; bf[7] = bhi[3];                      \
    acc = __builtin_amdgcn_mfma_scale_f32_32x32x64_f8f6f4(                               \
        af, bf, acc, 0, 0, 0, 0x7F7F7F7F, 0, 0x7F7F7F7F);                                \
  } while (0)

  // Prologue: 4 K-steps in flight (8 loads).
  ISSUE(0, 0);
  ISSUE(1, 64);
  ISSUE(2, 128);
  ISSUE(3, 192);
#pragma unroll
  for (int p = 0; p < 32; p++) {
    const int a = (2 * p) % 6;            // compile-time after full unroll
    if (p < 30) {
      const int na = (2 * p + 4) % 6;
      ISSUE(na, (2 * p + 4) * 64);
      ISSUE(na + 1, (2 * p + 5) * 64);
      __builtin_amdgcn_s_waitcnt(WAITCNT_VM8);   // 12 outstanding -> drain oldest pair
    } else if (p == 30) {
      __builtin_amdgcn_s_waitcnt(WAITCNT_VM4);
    } else {
      __builtin_amdgcn_s_waitcnt(WAITCNT_VM0);
    }
    __builtin_amdgcn_sched_barrier(0);
    __builtin_amdgcn_s_barrier();
    __builtin_amdgcn_s_setprio(1);
    COMPUTE(a);
    COMPUTE(a + 1);
    __builtin_amdgcn_s_setprio(0);
    if (p < 31) {
      __builtin_amdgcn_s_barrier();
      __builtin_amdgcn_sched_barrier(0);
    }
  }

#undef ISSUE
#undef COMPUTE

  // ---- fused epilogue (LDS reused; sync guards last-stage readers) ----
  // 32x32 C/D layout: col = lane&31, row = (reg&3) + 8*(reg>>2) + 4*(lane>>5).
  float* tileE   = (float*)lds;                 // [64][65] float (16640 B)
  float* colpart = (float*)(lds + 16640);       // [2][64]        (512 B)
  __syncthreads();

  // Phase 1: exp, col partial sums, numerator extraction.
  {
    const int col = wc * 32 + (lane & 31);
    float evsum = 0.f;
#pragma unroll
    for (int i = 0; i < 16; i++) {
      const int row = wr * 32 + (i & 3) + 8 * (i >> 2) + 4 * (lane >> 5);
      const float v = acc[i] * OUT_SCALE;
      const float ev = __expf(v);
      tileE[row * 65 + col] = ev;
      evsum += ev;
      const int D = (gc + col - gr - row) & (NROWS - 1);
      if (D == 4 || D == 12) num_store(NUM, gr + row, D, v);
      if (ti != tj && (D == 2044 || D == 2036)) num_store(NUM, gc + col, 2048 - D, v);
    }
    evsum += __shfl_xor(evsum, 32, 64);
    if (lane < 32) colpart[wr * 64 + col] = evsum;   // wave-unique slot, no atomic
  }
  __syncthreads();

  // Phase 2: four parallel thread groups.
  if (tid < 64) {
    // main-orientation window sums: rows R = gr+tid, cols [gc, gc+64)
    const int R = gr + tid;
#pragma unroll
    for (int k = 0; k < 6; k++) {
      const int aa = (R - 4 * k) & (NROWS - 1);
      if (aa % 12 < 4) {
        const int p2 = (aa / 12) * 4 + (aa % 12);
        const int c = aa & 3;
        const int j0 = ((gc >> 2) - (aa >> 2)) & 511;
        float w = 0.f;
#pragma unroll
        for (int i2 = 0; i2 < 16; i2++) {
          const int j = j0 + i2;
          if (j < 160 || j >= 512) w += tileE[tid * 65 + 4 * i2 + c];
        }
        atomicAdd(&WS[p2 * 6 + k], w);
      }
    }
  } else if (tid < 128) {
    // mirror-orientation window sums: rows R = gc+col, cols [gr, gr+64)
    if (ti != tj) {
      const int col = tid - 64;
      const int R = gc + col;
#pragma unroll
      for (int k = 0; k < 6; k++) {
        const int aa = (R - 4 * k) & (NROWS - 1);
        if (aa % 12 < 4) {
          const int p2 = (aa / 12) * 4 + (aa % 12);
          const int c = aa & 3;
          const int j0 = ((gr >> 2) - (aa >> 2)) & 511;
          float w = 0.f;
#pragma unroll
          for (int i2 = 0; i2 < 16; i2++) {
            const int j = j0 + i2;
            if (j < 160 || j >= 512) w += tileE[(4 * i2 + c) * 65 + col];
          }
          atomicAdd(&WS[p2 * 6 + k], w);
        }
      }
    }
  } else if (tid < 192) {
    // row sums -> T[gr+r] (off-diagonal only; diagonal covered by col sums)
    if (ti != tj) {
      const int r = tid - 128;
      float rs = 0.f;
#pragma unroll 8
      for (int c = 0; c < 64; c++) rs += tileE[r * 65 + c];
      atomicAdd(&T[gr + r], rs);
    }
  } else {
    // col sums -> T[gc+c] (symmetry: column sum == mirrored row sum)
    const int c = tid - 192;
    atomicAdd(&T[gc + c], colpart[c] + colpart[64 + c]);
  }
}

// ---- Kernel 3A: finisher. 19 blocks; Ds = T - WS; loss terms from NUM. ----
__global__ __launch_bounds__(256) void k_finalA(const float* __restrict__ NUM,
                                                const float* __restrict__ WS,
                                                const float* __restrict__ T,
                                                float* __restrict__ out) {
  const int pa[7] = {0, 1, 0, 3, 4, 1, 2};
  const int pb[7] = {1, 2, 3, 4, 5, 4, 5};
  const int idx = blockIdx.x * 256 + threadIdx.x;
  float s = 0.f;
  if (idx < NACT * 7) {
    const int p = idx / 7;
    const int q = idx - p * 7;
    const int a0 = 12 * (p >> 2) + (p & 3);
    const int ra = (a0 + 4 * pa[q]) & (NROWS - 1);
    const int rb = (a0 + 4 * pb[q]) & (NROWS - 1);
    const float dsA = T[ra] - WS[p * 6 + pa[q]];
    const float dsB = T[rb] - WS[p * 6 + pb[q]];
    const float num = NUM[idx];
    const float en = __expf(num);
    s = __logf(en + dsA) + __logf(en + dsB) - 2.f * num;
  }
#pragma unroll
  for (int off = 32; off > 0; off >>= 1) s += __shfl_down(s, off, 64);
  if ((threadIdx.x & 63) == 0) atomicAdd(out, s * (1.0f / (6.0f * 512.0f)));
}

// ------------- Path B kernels (fallback when ws is small; fp32 S) -------------
__global__ __launch_bounds__(256) void k_normconv(const float* __restrict__ X,
                                                  unsigned short* __restrict__ Y) {
  const int row = blockIdx.x;
  const float4* xr = (const float4*)(X + (size_t)row * DIM);
  float4 v[4];
  float s = 0.f;
#pragma unroll
  for (int t = 0; t < 4; t++) {
    float4 w = xr[threadIdx.x + t * 256];
    v[t] = w;
    s += w.x * w.x + w.y * w.y + w.z * w.z + w.w * w.w;
  }
#pragma unroll
  for (int off = 32; off > 0; off >>= 1) s += __shfl_down(s, off, 64);
  __shared__ float wsum[4];
  if ((threadIdx.x & 63) == 0) wsum[threadIdx.x >> 6] = s;
  __syncthreads();
  const float total = wsum[0] + wsum[1] + wsum[2] + wsum[3];
  const float inv = 1.0f / fmaxf(sqrtf(total), 1e-30f);
  ushort4* yr = (ushort4*)(Y + (size_t)row * DIM);
#pragma unroll
  for (int t = 0; t < 4; t++) {
    float4 w = v[t];
    ushort4 o;
    o.x = f32_to_bf16(w.x * inv);
    o.y = f32_to_bf16(w.y * inv);
    o.z = f32_to_bf16(w.z * inv);
    o.w = f32_to_bf16(w.w * inv);
    yr[threadIdx.x + t * 256] = o;
  }
}

__global__ __launch_bounds__(256) void k_gemm(const unsigned short* __restrict__ Y,
                                              float* __restrict__ S) {
  __shared__ __attribute__((aligned(16))) unsigned short sA[128 * 32];
  __shared__ __attribute__((aligned(16))) unsigned short sB[128 * 32];
  const int tid  = threadIdx.x;
  const int lane = tid & 63;
  const int wave = tid >> 6;
  const int wr = wave >> 1;
  const int wc = wave & 1;
  const int row0 = blockIdx.y * 128;
  const int col0 = blockIdx.x * 128;

  floatx4 zero = {0.f, 0.f, 0.f, 0.f};
  floatx4 acc[4][4];
#pragma unroll
  for (int i = 0; i < 4; i++)
#pragma unroll
    for (int j = 0; j < 4; j++) acc[i][j] = zero;

  const int sr = tid >> 2;
  const int sc = (tid & 3) * 8;
  const unsigned short* gA0 = Y + (size_t)(row0 + sr) * DIM + sc;
  const unsigned short* gA1 = gA0 + (size_t)64 * DIM;
  const unsigned short* gB0 = Y + (size_t)(col0 + sr) * DIM + sc;
  const unsigned short* gB1 = gB0 + (size_t)64 * DIM;

  const int fr = lane & 15;
  const int fc = (lane >> 4) * 8;

  for (int k0 = 0; k0 < DIM; k0 += 32) {
    __builtin_amdgcn_global_load_lds(
        (const __attribute__((address_space(1))) void*)(gA0 + k0),
        (__attribute__((address_space(3))) void*)(sA + tid * 8), 16, 0, 0);
    __builtin_amdgcn_global_load_lds(
        (const __attribute__((address_space(1))) void*)(gA1 + k0),
        (__attribute__((address_space(3))) void*)(sA + 2048 + tid * 8), 16, 0, 0);
    __builtin_amdgcn_global_load_lds(
        (const __attribute__((address_space(1))) void*)(gB0 + k0),
        (__attribute__((address_space(3))) void*)(sB + tid * 8), 16, 0, 0);
    __builtin_amdgcn_global_load_lds(
        (const __attribute__((address_space(1))) void*)(gB1 + k0),
        (__attribute__((address_space(3))) void*)(sB + 2048 + tid * 8), 16, 0, 0);
    __syncthreads();

    shortx8 af[4], bf[4];
#pragma unroll
    for (int mi = 0; mi < 4; mi++)
      af[mi] = *(const shortx8*)(sA + (wr * 64 + mi * 16 + fr) * 32 + fc);
#pragma unroll
    for (int ni = 0; ni < 4; ni++)
      bf[ni] = *(const shortx8*)(sB + (wc * 64 + ni * 16 + fr) * 32 + fc);
#pragma unroll
    for (int mi = 0; mi < 4; mi++)
#pragma unroll
      for (int ni = 0; ni < 4; ni++)
        acc[mi][ni] = __builtin_amdgcn_mfma_f32_16x16x32_bf16(af[mi], bf[ni], acc[mi][ni], 0, 0, 0);
    __syncthreads();
  }

  const int cc  = lane & 15;
  const int cr4 = (lane >> 4) * 4;
#pragma unroll
  for (int mi = 0; mi < 4; mi++) {
    const int row = row0 + wr * 64 + mi * 16 + cr4;
#pragma unroll
    for (int ni = 0; ni < 4; ni++) {
      const int col = col0 + wc * 64 + ni * 16 + cc;
      float* dst = S + (size_t)row * NROWS + col;
#pragma unroll
      for (int r = 0; r < 4; r++) dst[(size_t)r * NROWS] = acc[mi][ni][r] * INV_TEMP;
    }
  }
}

__global__ __launch_bounds__(256) void k_rowsum(const float* __restrict__ S,
                                                float* __restrict__ T) {
  const int row = blockIdx.x;
  const float* sr = S + (size_t)row * NROWS;
  float s = 0.f;
  for (int b = threadIdx.x; b < NROWS; b += 256) s += __expf(sr[b]);
#pragma unroll
  for (int off = 32; off > 0; off >>= 1) s += __shfl_down(s, off, 64);
  __shared__ float wsum[4];
  if ((threadIdx.x & 63) == 0) wsum[threadIdx.x >> 6] = s;
  __syncthreads();
  if (threadIdx.x == 0) T[row] = wsum[0] + wsum[1] + wsum[2] + wsum[3];
}

__global__ __launch_bounds__(64) void k_dsum(const float* __restrict__ S,
                                             const float* __restrict__ T,
                                             float* __restrict__ Ds) {
  const int p = blockIdx.x;
  const int k = blockIdx.y;
  const int a = 12 * (p >> 2) + (p & 3);
  const int lane = threadIdx.x;
  const int row = (a + 4 * k) & (NROWS - 1);
  const int m = a >> 2;
  const int c = a & 3;
  const float4* sr4 = (const float4*)(S + (size_t)row * NROWS);
  float s = 0.f;
  {
    float4 v0 = sr4[(m + lane) & 511];
    float4 v1 = sr4[(m + 64 + lane) & 511];
    float e0 = c == 0 ? v0.x : c == 1 ? v0.y : c == 2 ? v0.z : v0.w;
    float e1 = c == 0 ? v1.x : c == 1 ? v1.y : c == 2 ? v1.z : v1.w;
    s += __expf(e0) + __expf(e1);
    if (lane < 32) {
      float4 v2 = sr4[(m + 128 + lane) & 511];
      float e2 = c == 0 ? v2.x : c == 1 ? v2.y : c == 2 ? v2.z : v2.w;
      s += __expf(e2);
    }
  }
#pragma unroll
  for (int off = 32; off > 0; off >>= 1) s += __shfl_down(s, off, 64);
  if (lane == 0) Ds[p * 6 + k] = T[row] - s;
}

__global__ __launch_bounds__(256) void k_final(const float* __restrict__ S,
                                               const float* __restrict__ Ds,
                                               float* __restrict__ out) {
  const int pa[7] = {0, 1, 0, 3, 4, 1, 2};
  const int pb[7] = {1, 2, 3, 4, 5, 4, 5};
  const int idx = blockIdx.x * 256 + threadIdx.x;
  float s = 0.f;
  if (idx < NACT * 7) {
    const int p = idx / 7;
    const int q = idx - p * 7;
    const int a0 = 12 * (p >> 2) + (p & 3);
    const int ra = (a0 + 4 * pa[q]) & (NROWS - 1);
    const int rb = (a0 + 4 * pb[q]) & (NROWS - 1);
    const float num = S[(size_t)ra * NROWS + rb];
    const float en = __expf(num);
    s = __logf(en + Ds[p * 6 + pa[q]]) + __logf(en + Ds[p * 6 + pb[q]]) - 2.f * num;
  }
#pragma unroll
  for (int off = 32; off > 0; off >>= 1) s += __shfl_down(s, off, 64);
  if ((threadIdx.x & 63) == 0) atomicAdd(out, s * (1.0f / (6.0f * 512.0f)));
}

extern "C" void kernel_launch(void* const* d_in, const int* in_sizes, int n_in,
                              void* d_out, int out_size, void* d_ws, size_t ws_size,
                              hipStream_t stream) {
  const float* X = (const float*)d_in[0];
  char* ws = (char*)d_ws;
  float* out = (float*)d_out;

  const size_t pOff = (size_t)32 * 1024 * 1024;
  const size_t needA = pOff + 8192 + 24576 + 24576;   // T + WS + NUM

  if (ws_size >= needA) {
    unsigned char* Yq = (unsigned char*)ws;            // 8 MB fp8
    float* T   = (float*)(ws + pOff);                  // 2048 f32
    float* WS  = (float*)(ws + pOff + 8192);           // 4104 f32 window sums
    float* NUM = (float*)(ws + pOff + 8192 + 24576);   // 4788 f32 pair numerators
    hipLaunchKernelGGL(k_normconv_fp8, dim3(NROWS), dim3(256), 0, stream, X, Yq, T, WS, out);
    hipLaunchKernelGGL(k_gemm_full, dim3(NTILE64), dim3(256), 0, stream, Yq, T, WS, NUM);
    hipLaunchKernelGGL(k_finalA, dim3((NACT * 7 + 255) / 256), dim3(256), 0, stream,
                       NUM, WS, T, out);
  } else {
    unsigned short* Y = (unsigned short*)ws;                      // 16 MB bf16
    float* S = (float*)(ws + (size_t)16 * 1024 * 1024);           // 16 MB fp32
    float* T  = (float*)(ws + pOff);
    float* Ds = (float*)(ws + pOff + 8192);
    hipMemsetAsync(out, 0, sizeof(float), stream);
    hipLaunchKernelGGL(k_normconv, dim3(NROWS), dim3(256), 0, stream, X, Y);
    hipLaunchKernelGGL(k_gemm, dim3(16, 16), dim3(256), 0, stream, Y, S);
    hipLaunchKernelGGL(k_rowsum, dim3(NROWS), dim3(256), 0, stream, S, T);
    hipLaunchKernelGGL(k_dsum, dim3(NACT, 6), dim3(64), 0, stream, S, T, Ds);
    hipLaunchKernelGGL(k_final, dim3((NACT * 7 + 255) / 256), dim3(256), 0, stream, S, Ds, out);
  }
}